// Round 4
// baseline (360.778 us; speedup 1.0000x reference)
//
#include <hip/hip_runtime.h>
#include <cstdint>

#define BN 4
#define CIN 256
#define HALFC 128
#define HW 4096
#define SPLIT 4
#define JT 64
#define JITERS (HW / SPLIT / JT)   // 16

typedef float  floatx4 __attribute__((ext_vector_type(4)));
typedef short  shortx8 __attribute__((ext_vector_type(8)));

#if __has_builtin(__builtin_amdgcn_exp2f)
#define EXP2F(x) __builtin_amdgcn_exp2f(x)
#else
#define EXP2F(x) exp2f(x)
#endif
#define L2E 1.44269504088896f

__device__ __forceinline__ unsigned short f2bf(float f) {
  unsigned u = __float_as_uint(f);
  u += 0x7FFFu + ((u >> 16) & 1u);   // round-to-nearest-even
  return (unsigned short)(u >> 16);
}
__device__ __forceinline__ float bf2f(unsigned short h) {
  return __uint_as_float((unsigned)h << 16);
}

__device__ __forceinline__ void async16(const void* g, void* l) {
  __builtin_amdgcn_global_load_lds((const __attribute__((address_space(1))) void*)g,
                                   (__attribute__((address_space(3))) void*)l, 16, 0, 0);
}

// ---------------- K0: split x -> Xt (transposed [b][px][ci], bf16 hi/lo); W -> Wh/Wl ---
// grid 1024+12: bid<1024 transpose-split x; bid>=1024 split w1|w2|w3 into Wh/Wl[384][256].
__global__ __launch_bounds__(256) void k_split(const float* __restrict__ x,
    const float* __restrict__ w1, const float* __restrict__ w2,
    const float* __restrict__ w3, unsigned short* __restrict__ Xth,
    unsigned short* __restrict__ Xtl, unsigned short* __restrict__ Wh,
    unsigned short* __restrict__ Wl) {
  __shared__ float smf[64 * 65];
  int bid = blockIdx.x;
  int t = threadIdx.x;
  if (bid < 1024) {
    int b = bid >> 8, rem = bid & 255;
    int cit = rem >> 6, pxt = rem & 63;     // ci tile (4), px tile (64)
    const float* src = x + (size_t)b * 1048576 + (size_t)(cit * 64) * HW + pxt * 64;
#pragma unroll
    for (int k = 0; k < 16; k++) {
      int idx = k * 256 + t;
      int r = idx >> 6, c = idx & 63;
      smf[r * 65 + c] = src[(size_t)r * HW + c];
    }
    __syncthreads();
    int prow = t >> 2, seg = t & 3;
    union { unsigned short us[16]; uint4 v[2]; } oh, ol;
#pragma unroll
    for (int u = 0; u < 16; u++) {
      float v = smf[(seg * 16 + u) * 65 + prow];
      unsigned short hh = f2bf(v);
      oh.us[u] = hh;
      ol.us[u] = f2bf(v - bf2f(hh));
    }
    size_t dst = (size_t)b * 1048576 + (size_t)(pxt * 64 + prow) * 256 + cit * 64 + seg * 16;
    *(uint4*)(Xth + dst) = oh.v[0];
    *(uint4*)(Xth + dst + 8) = oh.v[1];
    *(uint4*)(Xtl + dst) = ol.v[0];
    *(uint4*)(Xtl + dst + 8) = ol.v[1];
  } else {
    int bw = bid - 1024;                    // 0..11, each block 8192 elems
    int f0 = bw * 8192 + t * 32;
    const float* wsrc;
    int fo;
    if (f0 < 32768)      { wsrc = w1; fo = f0; }
    else if (f0 < 65536) { wsrc = w2; fo = f0 - 32768; }
    else                 { wsrc = w3; fo = f0 - 65536; }
    union { unsigned short us[32]; uint4 v[4]; } oh, ol;
#pragma unroll
    for (int u = 0; u < 32; u++) {
      float v = wsrc[fo + u];
      unsigned short hh = f2bf(v);
      oh.us[u] = hh;
      ol.us[u] = f2bf(v - bf2f(hh));
    }
#pragma unroll
    for (int k = 0; k < 4; k++) {
      *((uint4*)(Wh + f0) + k) = oh.v[k];
      *((uint4*)(Wl + f0) + k) = ol.v[k];
    }
  }
}

// ---------------- K1: MFMA projection (bf16-split, fp32 acc) ---------------------------
// GEMM: n[co][px] = sum_ci W[co][ci] * x[ci][px], co in [0,384), per b.
// A = Xt[px][ci] (M=px), B = W[co][ci] (N=co). 3 products: wh*xh + wh*xl + wl*xh.
// grid 768 = b(4) x cot(6) x pxt(32); block: [64 co][128 px]; wave w: co [co0+16w,+16).
// Epilogue: cot 0,1 -> Q flat; cot 2,3 -> Kt (transposed); cot 4,5 -> n3 [ch][px].
__global__ __launch_bounds__(256) void k_projM(const unsigned short* __restrict__ Xth,
    const unsigned short* __restrict__ Xtl, const unsigned short* __restrict__ Wh,
    const unsigned short* __restrict__ Wl, unsigned short* __restrict__ Q,
    unsigned short* __restrict__ Kt, unsigned short* __restrict__ n3) {
  __shared__ unsigned short XhS[4096];   // [128 px][32 ci], 16B-granule xor-swizzled
  __shared__ unsigned short XlS[4096];
  __shared__ unsigned short ES[9216];    // epilogue stage: max(64*136, 128*72)
  int bid = blockIdx.x;
  int pxt = bid & 31;
  int ct = bid >> 5;                     // b*6 + cot
  int b = ct / 6, cot = ct % 6;
  int px0 = pxt * 128, co0 = cot * 64;
  int t = threadIdx.x;
  int w = t >> 6, lane = t & 63, l16 = lane & 15, quad = lane >> 4;

  // preload W fragments (B-operand): lane: co = co0+w*16+l16, k = s*32+quad*8+j
  int myco = co0 + w * 16 + l16;
  shortx8 whf[8], wlf[8];
#pragma unroll
  for (int s = 0; s < 8; s++) {
    whf[s] = *(const shortx8*)(Wh + (size_t)myco * 256 + s * 32 + quad * 8);
    wlf[s] = *(const shortx8*)(Wl + (size_t)myco * 256 + s * 32 + quad * 8);
  }
  floatx4 acc[8];
  floatx4 zf = {0.f, 0.f, 0.f, 0.f};
#pragma unroll
  for (int mt = 0; mt < 8; mt++) acc[mt] = zf;
  const unsigned short* XhB = Xth + (size_t)b * 1048576;
  const unsigned short* XlB = Xtl + (size_t)b * 1048576;

  for (int s = 0; s < 8; s++) {
    __syncthreads();
#pragma unroll
    for (int c2 = 0; c2 < 2; c2++) {     // stage [128 px][32 ci] h and l, swizzled
      int L = c2 * 256 + t;
      int r = L >> 2, g = L & 3;
      int gg = g ^ (r & 3);
      size_t so = (size_t)(px0 + r) * 256 + s * 32 + gg * 8;
      async16(XhB + so, (char*)XhS + c2 * 4096 + w * 1024);
      async16(XlB + so, (char*)XlS + c2 * 4096 + w * 1024);
    }
    __syncthreads();
#pragma unroll
    for (int mt = 0; mt < 8; mt++) {
      int r = mt * 16 + l16;
      int gsw = quad ^ (r & 3);
      shortx8 ah = *(const shortx8*)((const char*)XhS + r * 64 + gsw * 16);
      shortx8 al = *(const shortx8*)((const char*)XlS + r * 64 + gsw * 16);
      acc[mt] = __builtin_amdgcn_mfma_f32_16x16x32_bf16(ah, whf[s], acc[mt], 0, 0, 0);
      acc[mt] = __builtin_amdgcn_mfma_f32_16x16x32_bf16(al, whf[s], acc[mt], 0, 0, 0);
      acc[mt] = __builtin_amdgcn_mfma_f32_16x16x32_bf16(ah, wlf[s], acc[mt], 0, 0, 0);
    }
  }
  __syncthreads();
  // D layout: element [px = mt*16 + quad*4 + rr][co_l = w*16 + l16]
  if (cot < 2 || cot >= 4) {             // Q / n3: need [co][px] rows -> stage [co][px]
    int co_l = w * 16 + l16;
#pragma unroll
    for (int mt = 0; mt < 8; mt++) {
      int px = mt * 16 + quad * 4;
      unsigned lo = (unsigned)f2bf(acc[mt][0]) | ((unsigned)f2bf(acc[mt][1]) << 16);
      unsigned hi = (unsigned)f2bf(acc[mt][2]) | ((unsigned)f2bf(acc[mt][3]) << 16);
      *(uint2*)(ES + co_l * 136 + px) = make_uint2(lo, hi);
    }
    __syncthreads();
    int cr = t >> 2, seg = t & 3;
    unsigned short* dstb = (cot < 2)
        ? Q  + (size_t)b * 524288 + (size_t)(co0 + cr) * HW
        : n3 + (size_t)b * 524288 + (size_t)(co0 - 256 + cr) * HW;
#pragma unroll
    for (int k2 = 0; k2 < 4; k2++) {
      uint4 v = *(const uint4*)(ES + cr * 136 + seg * 32 + k2 * 8);
      *(uint4*)(dstb + px0 + seg * 32 + k2 * 8) = v;
    }
  } else {                               // Kt: need [px][ch'] rows -> stage [px][co]
#pragma unroll
    for (int mt = 0; mt < 8; mt++)
#pragma unroll
      for (int rr = 0; rr < 4; rr++) {
        int px = mt * 16 + quad * 4 + rr;
        ES[px * 72 + w * 16 + l16] = f2bf(acc[mt][rr]);
      }
    __syncthreads();
    int ch0 = co0 - 128;
#pragma unroll
    for (int it = 0; it < 4; it++) {
      int cid = it * 256 + t;
      int px = cid >> 3, c8 = cid & 7;
      uint4 v = *(const uint4*)(ES + px * 72 + c8 * 8);
      *(uint4*)(Kt + (size_t)b * 524288 + (size_t)(px0 + px) * 128 + ch0 + c8 * 8) = v;
    }
  }
}

// ---------------- K2: Vt shuffle: Vt[b][c][j] = n3[j>>5][((j&31)<<7)+c] ---------------
__global__ __launch_bounds__(256) void k_layoutV(const unsigned short* __restrict__ n3,
    unsigned short* __restrict__ Vt) {
  __shared__ unsigned short sm[8192];
  int bid = blockIdx.x;
  int t = threadIdx.x;
  int b = bid >> 6;
  int chg = bid & 63;
  const unsigned short* src = n3 + (size_t)b * 524288 + (size_t)(chg * 2) * HW;
#pragma unroll
  for (int k = 0; k < 32; k++) {
    int idx = k * 256 + t;
    sm[idx] = src[idx];
  }
  __syncthreads();
  int c = t >> 1, half = t & 1;
  union { unsigned short us[32]; uint4 v[4]; } o;
#pragma unroll
  for (int u = 0; u < 32; u++) o.us[u] = sm[half * 4096 + u * 128 + c];
  unsigned short* d = Vt + ((size_t)b * 128 + c) * HW + chg * 64 + half * 32;
#pragma unroll
  for (int k = 0; k < 4; k++) *((uint4*)d + k) = o.v[k];
}

// ---------------- K3: fused flash attention (bf16 MFMA, split-j) -----------------------
// Computes S^T[j][i] = Kt*Q^T tiles, online softmax over j, O[i][c] += P*V.
// grid: 1024 = b(4) x sp(4) x itile(64); block 256 (4 waves), wave owns 16 i.
__global__ __launch_bounds__(256, 4) void k_flash(const unsigned short* __restrict__ Q,
    const unsigned short* __restrict__ Kt, const unsigned short* __restrict__ Vt,
    float* __restrict__ Opart, float* __restrict__ ml) {
  __shared__ unsigned short KtS[64 * 128];   // [j][c] rows 256B, 16B-block xor-swizzled
  __shared__ unsigned short VtS[128 * 64];   // [c][j] rows 128B, swizzled
  __shared__ unsigned short PS[4 * 16 * 64]; // per-wave [i][j], 16B-granule swizzled
  int bid = blockIdx.x;
  int itile = bid & 63, sp = (bid >> 6) & 3, b = bid >> 8;
  int t = threadIdx.x;
  int w = t >> 6, lane = t & 63, l16 = lane & 15, quad = lane >> 4;
  int i0 = itile * 64;

  shortx8 qf[4];   // B-frags of Q for this wave's 16 i (resident whole kernel)
  {
    const unsigned short* qp = Q + ((size_t)b * HW + i0 + w * 16 + l16) * 128 + quad * 8;
#pragma unroll
    for (int ks = 0; ks < 4; ks++) qf[ks] = *(const shortx8*)(qp + ks * 32);
  }
  floatx4 O[8];
  floatx4 zf = {0.f, 0.f, 0.f, 0.f};
#pragma unroll
  for (int nt = 0; nt < 8; nt++) O[nt] = zf;
  float m_i = -1e30f, l_i = 0.f;
  const unsigned short* KtB = Kt + (size_t)b * HW * 128;
  const unsigned short* VtB = Vt + (size_t)b * 128 * HW;
  unsigned short* Pw = PS + w * 1024;

  for (int it = 0; it < JITERS; it++) {
    int j0 = sp * (HW / SPLIT) + it * JT;
    __syncthreads();                       // previous tile fully consumed
#pragma unroll
    for (int c4 = 0; c4 < 4; c4++) {       // stage Kt tile [64 j][128 c], swizzle at source
      int L = c4 * 256 + t;
      int r = L >> 4, xs = L & 15;
      int xx = xs ^ (r & 7);
      async16(KtB + (size_t)(j0 + r) * 128 + xx * 8, (char*)KtS + c4 * 4096 + w * 1024);
    }
#pragma unroll
    for (int c4 = 0; c4 < 4; c4++) {       // stage Vt tile [128 c][64 j]
      int L = c4 * 256 + t;
      int r = L >> 3, xs = L & 7;
      int xx = xs ^ (r & 7);
      async16(VtB + (size_t)r * HW + j0 + xx * 8, (char*)VtS + c4 * 4096 + w * 1024);
    }
    __syncthreads();                       // vmcnt drain + barrier

    // ---- QK: S^T[j][i], wave: all 64 j x its 16 i ----
    floatx4 S[4];
#pragma unroll
    for (int mt = 0; mt < 4; mt++) S[mt] = zf;
#pragma unroll
    for (int mt = 0; mt < 4; mt++) {
      int r = mt * 16 + l16;
#pragma unroll
      for (int ks = 0; ks < 4; ks++) {
        int xx = (quad + ks * 4) ^ (r & 7);
        shortx8 af = *(const shortx8*)((const char*)KtS + r * 256 + xx * 16);
        S[mt] = __builtin_amdgcn_mfma_f32_16x16x32_bf16(af, qf[ks], S[mt], 0, 0, 0);
      }
    }
    // ---- online softmax over j, per column i = l16 ----
    float tmax = S[0][0];
#pragma unroll
    for (int mt = 0; mt < 4; mt++)
#pragma unroll
      for (int rr = 0; rr < 4; rr++) tmax = fmaxf(tmax, S[mt][rr]);
    tmax = fmaxf(tmax, __shfl_xor(tmax, 16));
    tmax = fmaxf(tmax, __shfl_xor(tmax, 32));
    float mnew = fmaxf(m_i, tmax);
    float alpha = EXP2F((m_i - mnew) * L2E);
    float tsum = 0.f;
    float P[4][4];
#pragma unroll
    for (int mt = 0; mt < 4; mt++)
#pragma unroll
      for (int rr = 0; rr < 4; rr++) {
        float p = EXP2F((S[mt][rr] - mnew) * L2E);
        P[mt][rr] = p;
        tsum += p;
      }
    tsum += __shfl_xor(tsum, 16);
    tsum += __shfl_xor(tsum, 32);
    l_i = l_i * alpha + tsum;
    m_i = mnew;
    // O rows are i = quad*4+rr (C layout of PV) — fetch matching alpha via shfl
    float ar[4];
#pragma unroll
    for (int rr = 0; rr < 4; rr++) ar[rr] = __shfl(alpha, quad * 4 + rr);
#pragma unroll
    for (int nt = 0; nt < 8; nt++)
#pragma unroll
      for (int rr = 0; rr < 4; rr++) O[nt][rr] *= ar[rr];
    // ---- P -> wave-private LDS [i][j] (C-layout -> A-layout transform) ----
#pragma unroll
    for (int mt = 0; mt < 4; mt++) {
      int jl = mt * 16 + quad * 4;
      unsigned lo = (unsigned)f2bf(P[mt][0]) | ((unsigned)f2bf(P[mt][1]) << 16);
      unsigned hi = (unsigned)f2bf(P[mt][2]) | ((unsigned)f2bf(P[mt][3]) << 16);
      uint2 val = make_uint2(lo, hi);
      int addr = l16 * 64 + (((jl >> 3) ^ (l16 & 7)) << 3) + (jl & 7);
      *(uint2*)(Pw + addr) = val;
    }
    __threadfence_block();                 // intra-wave LDS write->read ordering
    // ---- PV: O[i][c] += P[i][j] * V[j][c] ----
#pragma unroll
    for (int kt = 0; kt < 2; kt++) {
      int G0 = quad + kt * 4;
      shortx8 pf = *(const shortx8*)(Pw + l16 * 64 + ((G0 ^ (l16 & 7)) << 3));
#pragma unroll
      for (int nt = 0; nt < 8; nt++) {
        int r = nt * 16 + l16;
        int xx = G0 ^ (r & 7);
        shortx8 vf = *(const shortx8*)((const char*)VtS + r * 128 + xx * 16);
        O[nt] = __builtin_amdgcn_mfma_f32_16x16x32_bf16(pf, vf, O[nt], 0, 0, 0);
      }
    }
  }
  // epilogue: store partial O and (m,l)
  float* Ob = Opart + ((size_t)(sp * 4 + b) * HW + i0 + w * 16) * 128;
#pragma unroll
  for (int nt = 0; nt < 8; nt++)
#pragma unroll
    for (int rr = 0; rr < 4; rr++)
      Ob[(size_t)(quad * 4 + rr) * 128 + nt * 16 + l16] = O[nt][rr];
  if (quad == 0) {
    float2* mlp = (float2*)ml;
    mlp[(size_t)(sp * 4 + b) * HW + i0 + w * 16 + l16] = make_float2(m_i, l_i);
  }
}

// ---------------- K4: merge split-j partials -> res (flat == resmap layout) -----------
__global__ __launch_bounds__(256) void k_merge(const float* __restrict__ Opart,
    const float* __restrict__ ml, float* __restrict__ res) {
  size_t e = (size_t)blockIdx.x * 256 + threadIdx.x;  // float4 index
  int cq = (int)(e & 31);
  int i = (int)((e >> 5) & 4095);
  int b = (int)(e >> 17);
  const float2* mlp = (const float2*)ml;
  float m[SPLIT], l[SPLIT];
  float M = -1e30f;
#pragma unroll
  for (int s = 0; s < SPLIT; s++) {
    float2 st = mlp[(size_t)(s * 4 + b) * HW + i];
    m[s] = st.x; l[s] = st.y;
    M = fmaxf(M, m[s]);
  }
  float denom = 0.f;
  float wgt[SPLIT];
#pragma unroll
  for (int s = 0; s < SPLIT; s++) {
    float ws_ = EXP2F((m[s] - M) * L2E);
    wgt[s] = ws_;
    denom += l[s] * ws_;
  }
  float inv = 1.f / denom;
  floatx4 acc = {0.f, 0.f, 0.f, 0.f};
#pragma unroll
  for (int s = 0; s < SPLIT; s++) {
    floatx4 v = *(const floatx4*)(Opart + ((size_t)(s * 4 + b) * HW + i) * 128 + cq * 4);
    acc += v * (wgt[s] * inv);
  }
  *(floatx4*)(res + e * 4) = acc;
}

// ---------------- K5: conv4 (fp32) + BN(eval) + residual ------------------------------
// grid 1024 = b(4) x st(16) x cot(16); thread: 16 co x 1 px.
__global__ __launch_bounds__(256) void k_out(const float* __restrict__ res,
    const float* __restrict__ w4, const float* __restrict__ gamma,
    const float* __restrict__ beta, const float* __restrict__ rmean,
    const float* __restrict__ rvar, const float* __restrict__ x,
    float* __restrict__ out) {
  __shared__ float wt[16 * 128];
  int bid = blockIdx.x;
  int cot = bid & 15;
  int st = (bid >> 4) & 15;
  int b = bid >> 8;
  int t = threadIdx.x;
  int co0 = cot * 16;
#pragma unroll
  for (int k = 0; k < 8; k++) wt[k * 256 + t] = w4[(size_t)co0 * 128 + k * 256 + t];
  __syncthreads();
  int px = st * 256 + t;
  const float* rb = res + (size_t)b * 524288 + px;
  float acc[16];
#pragma unroll
  for (int r = 0; r < 16; r++) acc[r] = 0.f;
  for (int ci = 0; ci < 128; ci += 4) {
    float xv[4];
#pragma unroll
    for (int kk = 0; kk < 4; kk++) xv[kk] = rb[(size_t)(ci + kk) * HW];
#pragma unroll
    for (int r = 0; r < 16; r++) {
      floatx4 wv = *(const floatx4*)&wt[r * 128 + ci];
#pragma unroll
      for (int kk = 0; kk < 4; kk++) acc[r] += wv[kk] * xv[kk];
    }
  }
  const float* xb = x + ((size_t)b * 256 + co0) * HW + px;
  float* ob = out + ((size_t)b * 256 + co0) * HW + px;
#pragma unroll
  for (int r = 0; r < 16; r++) {
    int co = co0 + r;
    float g = gamma[co] * rsqrtf(rvar[co] + 1e-5f);
    float bb = beta[co] - rmean[co] * g;
    ob[(size_t)r * HW] = acc[r] * g + bb + xb[(size_t)r * HW];
  }
}

extern "C" void kernel_launch(void* const* d_in, const int* in_sizes, int n_in,
                              void* d_out, int out_size, void* d_ws, size_t ws_size,
                              hipStream_t stream) {
  const float* x     = (const float*)d_in[0];
  const float* w1    = (const float*)d_in[1];
  const float* w2    = (const float*)d_in[2];
  const float* w3    = (const float*)d_in[3];
  const float* w4    = (const float*)d_in[4];
  const float* gamma = (const float*)d_in[5];
  const float* beta  = (const float*)d_in[6];
  const float* rmean = (const float*)d_in[7];
  const float* rvar  = (const float*)d_in[8];
  float* out = (float*)d_out;
  char* ws = (char*)d_ws;

  // Opart region (32 MB) overlaps n3 / Xth / Xtl (all dead before k_flash runs)
  size_t off = (size_t)SPLIT * 4 * HW * 128 * 4;             // 32 MB
  float* Opart = (float*)ws;
  unsigned short* n3  = (unsigned short*)ws;                  // 4.2 MB @ 0
  unsigned short* Xth = (unsigned short*)(ws + ((size_t)8  << 20));  // 8.4 MB @ 8M
  unsigned short* Xtl = (unsigned short*)(ws + ((size_t)17 << 20));  // 8.4 MB @ 17M
  unsigned short* Q  = (unsigned short*)(ws + off); off += (size_t)4 * HW * 128 * 2;
  unsigned short* Kt = (unsigned short*)(ws + off); off += (size_t)4 * HW * 128 * 2;
  unsigned short* Vt = (unsigned short*)(ws + off); off += (size_t)4 * HW * 128 * 2;
  float* ml  = (float*)(ws + off); off += (size_t)SPLIT * 4 * HW * 2 * 4;
  float* res = (float*)(ws + off); off += (size_t)4 * HW * 128 * 4;
  unsigned short* Wh = (unsigned short*)(ws + off); off += (size_t)384 * 256 * 2;
  unsigned short* Wl = (unsigned short*)(ws + off); off += (size_t)384 * 256 * 2;
  if (ws_size < off) return;  // insufficient workspace: bail (validation will flag)

  k_split  <<<1036, 256, 0, stream>>>(x, w1, w2, w3, Xth, Xtl, Wh, Wl);
  k_projM  <<<768,  256, 0, stream>>>(Xth, Xtl, Wh, Wl, Q, Kt, n3);
  k_layoutV<<<256,  256, 0, stream>>>(n3, Vt);
  k_flash  <<<1024, 256, 0, stream>>>(Q, Kt, Vt, Opart, ml);
  k_merge  <<<2048, 256, 0, stream>>>(Opart, ml, res);
  k_out    <<<1024, 256, 0, stream>>>(res, w4, gamma, beta, rmean, rvar, x, out);
}

// Round 5
// 224.616 us; speedup vs baseline: 1.6062x; 1.6062x over previous
//
#include <hip/hip_runtime.h>
#include <cstdint>

#define BN 4
#define CIN 256
#define HALFC 128
#define HW 4096
#define SPLIT 4
#define JT 64
#define JITERS (HW / SPLIT / JT)   // 16

typedef float  floatx4 __attribute__((ext_vector_type(4)));
typedef short  shortx8 __attribute__((ext_vector_type(8)));

#if __has_builtin(__builtin_amdgcn_exp2f)
#define EXP2F(x) __builtin_amdgcn_exp2f(x)
#else
#define EXP2F(x) exp2f(x)
#endif
#define L2E 1.44269504088896f

__device__ __forceinline__ unsigned short f2bf(float f) {
  unsigned u = __float_as_uint(f);
  u += 0x7FFFu + ((u >> 16) & 1u);   // round-to-nearest-even
  return (unsigned short)(u >> 16);
}
__device__ __forceinline__ float bf2f(unsigned short h) {
  return __uint_as_float((unsigned)h << 16);
}

__device__ __forceinline__ void async16(const void* g, void* l) {
  __builtin_amdgcn_global_load_lds((const __attribute__((address_space(1))) void*)g,
                                   (__attribute__((address_space(3))) void*)l, 16, 0, 0);
}

// ---------------- K0: split x -> Xt (transposed [b][px][ci], bf16 hi/lo); W -> Wh/Wl ---
__global__ __launch_bounds__(256) void k_split(const float* __restrict__ x,
    const float* __restrict__ w1, const float* __restrict__ w2,
    const float* __restrict__ w3, unsigned short* __restrict__ Xth,
    unsigned short* __restrict__ Xtl, unsigned short* __restrict__ Wh,
    unsigned short* __restrict__ Wl) {
  __shared__ float smf[64 * 65];
  int bid = blockIdx.x;
  int t = threadIdx.x;
  if (bid < 1024) {
    int b = bid >> 8, rem = bid & 255;
    int cit = rem >> 6, pxt = rem & 63;     // ci tile (4), px tile (64)
    const float* src = x + (size_t)b * 1048576 + (size_t)(cit * 64) * HW + pxt * 64;
#pragma unroll
    for (int k = 0; k < 16; k++) {
      int idx = k * 256 + t;
      int r = idx >> 6, c = idx & 63;
      smf[r * 65 + c] = src[(size_t)r * HW + c];
    }
    __syncthreads();
    int prow = t >> 2, seg = t & 3;
    union { unsigned short us[16]; uint4 v[2]; } oh, ol;
#pragma unroll
    for (int u = 0; u < 16; u++) {
      float v = smf[(seg * 16 + u) * 65 + prow];
      unsigned short hh = f2bf(v);
      oh.us[u] = hh;
      ol.us[u] = f2bf(v - bf2f(hh));
    }
    size_t dst = (size_t)b * 1048576 + (size_t)(pxt * 64 + prow) * 256 + cit * 64 + seg * 16;
    *(uint4*)(Xth + dst) = oh.v[0];
    *(uint4*)(Xth + dst + 8) = oh.v[1];
    *(uint4*)(Xtl + dst) = ol.v[0];
    *(uint4*)(Xtl + dst + 8) = ol.v[1];
  } else {
    int bw = bid - 1024;                    // 0..11, each block 8192 elems
    int f0 = bw * 8192 + t * 32;
    const float* wsrc;
    int fo;
    if (f0 < 32768)      { wsrc = w1; fo = f0; }
    else if (f0 < 65536) { wsrc = w2; fo = f0 - 32768; }
    else                 { wsrc = w3; fo = f0 - 65536; }
    union { unsigned short us[32]; uint4 v[4]; } oh, ol;
#pragma unroll
    for (int u = 0; u < 32; u++) {
      float v = wsrc[fo + u];
      unsigned short hh = f2bf(v);
      oh.us[u] = hh;
      ol.us[u] = f2bf(v - bf2f(hh));
    }
#pragma unroll
    for (int k = 0; k < 4; k++) {
      *((uint4*)(Wh + f0) + k) = oh.v[k];
      *((uint4*)(Wl + f0) + k) = ol.v[k];
    }
  }
}

// ---------------- K1: MFMA projection (bf16-split, fp32 acc) ---------------------------
// LDS layout "fragment order": element for hw-lane L, fragment mt sits at mt*1024+L*16.
// XhS(px,k8): addr = (px>>4)*1024 + ((k8*16 + (px&15)))*16
__global__ __launch_bounds__(256) void k_projM(const unsigned short* __restrict__ Xth,
    const unsigned short* __restrict__ Xtl, const unsigned short* __restrict__ Wh,
    const unsigned short* __restrict__ Wl, unsigned short* __restrict__ Q,
    unsigned short* __restrict__ Kt, unsigned short* __restrict__ n3) {
  __shared__ unsigned short XhS[4096];   // [128 px][32 ci] in fragment order, 8 KB
  __shared__ unsigned short XlS[4096];
  __shared__ unsigned short ES[9216];    // epilogue stage
  int bid = blockIdx.x;
  int pxt = bid & 31;
  int ct = bid >> 5;                     // b*6 + cot
  int b = ct / 6, cot = ct % 6;
  int px0 = pxt * 128, co0 = cot * 64;
  int t = threadIdx.x;
  int w = t >> 6, lane = t & 63, l16 = lane & 15, quad = lane >> 4;

  // preload W fragments (B-operand): lane: co = co0+w*16+l16, k = s*32+quad*8+j
  int myco = co0 + w * 16 + l16;
  shortx8 whf[8], wlf[8];
#pragma unroll
  for (int s = 0; s < 8; s++) {
    whf[s] = *(const shortx8*)(Wh + (size_t)myco * 256 + s * 32 + quad * 8);
    wlf[s] = *(const shortx8*)(Wl + (size_t)myco * 256 + s * 32 + quad * 8);
  }
  floatx4 acc[8];
  floatx4 zf = {0.f, 0.f, 0.f, 0.f};
#pragma unroll
  for (int mt = 0; mt < 8; mt++) acc[mt] = zf;
  const unsigned short* XhB = Xth + (size_t)b * 1048576;
  const unsigned short* XlB = Xtl + (size_t)b * 1048576;
  int k8 = lane >> 4, pxm = lane & 15;

#pragma unroll
  for (int s = 0; s < 8; s++) {
    __syncthreads();
#pragma unroll
    for (int c2 = 0; c2 < 2; c2++) {     // stage fragment-order; lane L -> slot L*16
      int px = px0 + (c2 * 4 + w) * 16 + pxm;
      size_t so = (size_t)px * 256 + s * 32 + k8 * 8;
      async16(XhB + so, (char*)XhS + c2 * 4096 + w * 1024);
      async16(XlB + so, (char*)XlS + c2 * 4096 + w * 1024);
    }
    __syncthreads();
#pragma unroll
    for (int mt = 0; mt < 8; mt++) {
      shortx8 ah = *(const shortx8*)((const char*)XhS + mt * 1024 + lane * 16);
      shortx8 al = *(const shortx8*)((const char*)XlS + mt * 1024 + lane * 16);
      acc[mt] = __builtin_amdgcn_mfma_f32_16x16x32_bf16(ah, whf[s], acc[mt], 0, 0, 0);
      acc[mt] = __builtin_amdgcn_mfma_f32_16x16x32_bf16(al, whf[s], acc[mt], 0, 0, 0);
      acc[mt] = __builtin_amdgcn_mfma_f32_16x16x32_bf16(ah, wlf[s], acc[mt], 0, 0, 0);
    }
  }
  __syncthreads();
  // D layout: element [px = mt*16 + quad*4 + rr][co_l = w*16 + l16]
  if (cot < 2 || cot >= 4) {             // Q / n3: need [co][px] rows -> stage [co][px]
    int co_l = w * 16 + l16;
#pragma unroll
    for (int mt = 0; mt < 8; mt++) {
      int px = mt * 16 + quad * 4;
      unsigned lo = (unsigned)f2bf(acc[mt][0]) | ((unsigned)f2bf(acc[mt][1]) << 16);
      unsigned hi = (unsigned)f2bf(acc[mt][2]) | ((unsigned)f2bf(acc[mt][3]) << 16);
      *(uint2*)(ES + co_l * 136 + px) = make_uint2(lo, hi);
    }
    __syncthreads();
    int cr = t >> 2, seg = t & 3;
    unsigned short* dstb = (cot < 2)
        ? Q  + (size_t)b * 524288 + (size_t)(co0 + cr) * HW
        : n3 + (size_t)b * 524288 + (size_t)(co0 - 256 + cr) * HW;
#pragma unroll
    for (int k2 = 0; k2 < 4; k2++) {
      uint4 v = *(const uint4*)(ES + cr * 136 + seg * 32 + k2 * 8);
      *(uint4*)(dstb + px0 + seg * 32 + k2 * 8) = v;
    }
  } else {                               // Kt: need [px][ch'] rows -> stage [px][co]
#pragma unroll
    for (int mt = 0; mt < 8; mt++)
#pragma unroll
      for (int rr = 0; rr < 4; rr++) {
        int px = mt * 16 + quad * 4 + rr;
        ES[px * 72 + w * 16 + l16] = f2bf(acc[mt][rr]);
      }
    __syncthreads();
    int ch0 = co0 - 128;
#pragma unroll
    for (int it = 0; it < 4; it++) {
      int cid = it * 256 + t;
      int px = cid >> 3, c8 = cid & 7;
      uint4 v = *(const uint4*)(ES + px * 72 + c8 * 8);
      *(uint4*)(Kt + (size_t)b * 524288 + (size_t)(px0 + px) * 128 + ch0 + c8 * 8) = v;
    }
  }
}

// ---------------- K2: Vt shuffle: Vt[b][c][j] = n3[j>>5][((j&31)<<7)+c] ---------------
__global__ __launch_bounds__(256) void k_layoutV(const unsigned short* __restrict__ n3,
    unsigned short* __restrict__ Vt) {
  __shared__ unsigned short sm[8192];
  int bid = blockIdx.x;
  int t = threadIdx.x;
  int b = bid >> 6;
  int chg = bid & 63;
  const unsigned short* src = n3 + (size_t)b * 524288 + (size_t)(chg * 2) * HW;
#pragma unroll
  for (int k = 0; k < 32; k++) {
    int idx = k * 256 + t;
    sm[idx] = src[idx];
  }
  __syncthreads();
  int c = t >> 1, half = t & 1;
  union { unsigned short us[32]; uint4 v[4]; } o;
#pragma unroll
  for (int u = 0; u < 32; u++) o.us[u] = sm[half * 4096 + u * 128 + c];
  unsigned short* d = Vt + ((size_t)b * 128 + c) * HW + chg * 64 + half * 32;
#pragma unroll
  for (int k = 0; k < 4; k++) *((uint4*)d + k) = o.v[k];
}

// ---------------- K3: fused flash attention (bf16 MFMA, split-j) -----------------------
// All LDS tiles in fragment order: reads are lane-linear (conflict-free).
// KtS(j,cc):  (j>>4)*4096 + (cc*16 + (j&15))*16      cc = c-chunk 0..15
// VtS(c,cc):  (c>>4)*2048 + (cc*16 + (c&15))*16      cc = j-chunk 0..7
// PS(i,cc) per-wave: (cc*16 + i)*16                  cc = j-chunk 0..7
__global__ __launch_bounds__(256, 4) void k_flash(const unsigned short* __restrict__ Q,
    const unsigned short* __restrict__ Kt, const unsigned short* __restrict__ Vt,
    float* __restrict__ Opart, float* __restrict__ ml) {
  __shared__ unsigned short KtS[64 * 128];   // 16 KB
  __shared__ unsigned short VtS[128 * 64];   // 16 KB
  __shared__ unsigned short PS[4 * 16 * 64]; // 8 KB (2 KB per wave)
  int bid = blockIdx.x;
  int itile = bid & 63, sp = (bid >> 6) & 3, b = bid >> 8;
  int t = threadIdx.x;
  int w = t >> 6, lane = t & 63, l16 = lane & 15, quad = lane >> 4;
  int i0 = itile * 64;

  shortx8 qf[4];   // B-frags of Q for this wave's 16 i (resident whole kernel)
  {
    const unsigned short* qp = Q + ((size_t)b * HW + i0 + w * 16 + l16) * 128 + quad * 8;
#pragma unroll
    for (int ks = 0; ks < 4; ks++) qf[ks] = *(const shortx8*)(qp + ks * 32);
  }
  floatx4 O[8];
  floatx4 zf = {0.f, 0.f, 0.f, 0.f};
#pragma unroll
  for (int nt = 0; nt < 8; nt++) O[nt] = zf;
  float m_i = -1e30f, l_i = 0.f;
  const unsigned short* KtB = Kt + (size_t)b * HW * 128;
  const unsigned short* VtB = Vt + (size_t)b * 128 * HW;
  char* Pw = (char*)PS + w * 2048;

  for (int it = 0; it < JITERS; it++) {
    int j0 = sp * (HW / SPLIT) + it * JT;
    __syncthreads();                       // previous tile fully consumed
#pragma unroll
    for (int c4 = 0; c4 < 4; c4++) {       // stage Kt: super-row c4 (16 j x 128 c)
      int jm = lane & 15, cc = w * 4 + (lane >> 4);
      async16(KtB + (size_t)(j0 + c4 * 16 + jm) * 128 + cc * 8,
              (char*)KtS + c4 * 4096 + w * 1024);
    }
#pragma unroll
    for (int c4 = 0; c4 < 4; c4++) {       // stage Vt: super-row c4*2+(w>>1)
      int cm = lane & 15, cc = (w & 1) * 4 + (lane >> 4);
      int c = (c4 * 2 + (w >> 1)) * 16 + cm;
      async16(VtB + (size_t)c * HW + j0 + cc * 8,
              (char*)VtS + c4 * 4096 + w * 1024);
    }
    __syncthreads();                       // vmcnt drain + barrier

    // ---- QK: S^T[j][i], wave: all 64 j x its 16 i ----
    floatx4 S[4];
#pragma unroll
    for (int mt = 0; mt < 4; mt++) S[mt] = zf;
#pragma unroll
    for (int mt = 0; mt < 4; mt++) {
#pragma unroll
      for (int ks = 0; ks < 4; ks++) {
        shortx8 af = *(const shortx8*)((const char*)KtS + mt * 4096 + ks * 1024 + lane * 16);
        S[mt] = __builtin_amdgcn_mfma_f32_16x16x32_bf16(af, qf[ks], S[mt], 0, 0, 0);
      }
    }
    // ---- online softmax over j, per column i = l16 ----
    float tmax = S[0][0];
#pragma unroll
    for (int mt = 0; mt < 4; mt++)
#pragma unroll
      for (int rr = 0; rr < 4; rr++) tmax = fmaxf(tmax, S[mt][rr]);
    tmax = fmaxf(tmax, __shfl_xor(tmax, 16));
    tmax = fmaxf(tmax, __shfl_xor(tmax, 32));
    float mnew = fmaxf(m_i, tmax);
    float alpha = EXP2F((m_i - mnew) * L2E);
    float tsum = 0.f;
    float P[4][4];
#pragma unroll
    for (int mt = 0; mt < 4; mt++)
#pragma unroll
      for (int rr = 0; rr < 4; rr++) {
        float p = EXP2F((S[mt][rr] - mnew) * L2E);
        P[mt][rr] = p;
        tsum += p;
      }
    tsum += __shfl_xor(tsum, 16);
    tsum += __shfl_xor(tsum, 32);
    l_i = l_i * alpha + tsum;
    m_i = mnew;
    // O rows are i = quad*4+rr (C layout of PV) — fetch matching alpha via shfl
    float ar[4];
#pragma unroll
    for (int rr = 0; rr < 4; rr++) ar[rr] = __shfl(alpha, quad * 4 + rr);
#pragma unroll
    for (int nt = 0; nt < 8; nt++)
#pragma unroll
      for (int rr = 0; rr < 4; rr++) O[nt][rr] *= ar[rr];
    // ---- P -> wave-private LDS (C-layout -> A-frag order) ----
#pragma unroll
    for (int mt = 0; mt < 4; mt++) {
      unsigned lo = (unsigned)f2bf(P[mt][0]) | ((unsigned)f2bf(P[mt][1]) << 16);
      unsigned hi = (unsigned)f2bf(P[mt][2]) | ((unsigned)f2bf(P[mt][3]) << 16);
      int cc = mt * 2 + (quad >> 1);
      *(uint2*)(Pw + cc * 256 + l16 * 16 + (quad & 1) * 8) = make_uint2(lo, hi);
    }
    __threadfence_block();                 // intra-wave LDS write->read ordering
    // ---- PV: O[i][c] += P[i][j] * V[j][c] ----
#pragma unroll
    for (int kt = 0; kt < 2; kt++) {
      shortx8 pf = *(const shortx8*)(Pw + kt * 1024 + lane * 16);
#pragma unroll
      for (int nt = 0; nt < 8; nt++) {
        shortx8 vf = *(const shortx8*)((const char*)VtS + nt * 2048 + kt * 1024 + lane * 16);
        O[nt] = __builtin_amdgcn_mfma_f32_16x16x32_bf16(pf, vf, O[nt], 0, 0, 0);
      }
    }
  }
  // epilogue: store partial O and (m,l)
  float* Ob = Opart + ((size_t)(sp * 4 + b) * HW + i0 + w * 16) * 128;
#pragma unroll
  for (int nt = 0; nt < 8; nt++)
#pragma unroll
    for (int rr = 0; rr < 4; rr++)
      Ob[(size_t)(quad * 4 + rr) * 128 + nt * 16 + l16] = O[nt][rr];
  if (quad == 0) {
    float2* mlp = (float2*)ml;
    mlp[(size_t)(sp * 4 + b) * HW + i0 + w * 16 + l16] = make_float2(m_i, l_i);
  }
}

// ---------------- K4: merge split-j partials -> res (flat == resmap layout) -----------
__global__ __launch_bounds__(256) void k_merge(const float* __restrict__ Opart,
    const float* __restrict__ ml, float* __restrict__ res) {
  size_t e = (size_t)blockIdx.x * 256 + threadIdx.x;  // float4 index
  int cq = (int)(e & 31);
  int i = (int)((e >> 5) & 4095);
  int b = (int)(e >> 17);
  const float2* mlp = (const float2*)ml;
  float m[SPLIT], l[SPLIT];
  float M = -1e30f;
#pragma unroll
  for (int s = 0; s < SPLIT; s++) {
    float2 st = mlp[(size_t)(s * 4 + b) * HW + i];
    m[s] = st.x; l[s] = st.y;
    M = fmaxf(M, m[s]);
  }
  float denom = 0.f;
  float wgt[SPLIT];
#pragma unroll
  for (int s = 0; s < SPLIT; s++) {
    float ws_ = EXP2F((m[s] - M) * L2E);
    wgt[s] = ws_;
    denom += l[s] * ws_;
  }
  float inv = 1.f / denom;
  floatx4 acc = {0.f, 0.f, 0.f, 0.f};
#pragma unroll
  for (int s = 0; s < SPLIT; s++) {
    floatx4 v = *(const floatx4*)(Opart + ((size_t)(s * 4 + b) * HW + i) * 128 + cq * 4);
    acc += v * (wgt[s] * inv);
  }
  *(floatx4*)(res + e * 4) = acc;
}

// ---------------- K5: conv4 (fp32) + BN(eval) + residual ------------------------------
// grid 1024 = b(4) x st(16) x cot(16); thread: 16 co x 1 px.
__global__ __launch_bounds__(256) void k_out(const float* __restrict__ res,
    const float* __restrict__ w4, const float* __restrict__ gamma,
    const float* __restrict__ beta, const float* __restrict__ rmean,
    const float* __restrict__ rvar, const float* __restrict__ x,
    float* __restrict__ out) {
  __shared__ float wt[16 * 128];
  int bid = blockIdx.x;
  int cot = bid & 15;
  int st = (bid >> 4) & 15;
  int b = bid >> 8;
  int t = threadIdx.x;
  int co0 = cot * 16;
#pragma unroll
  for (int k = 0; k < 8; k++) wt[k * 256 + t] = w4[(size_t)co0 * 128 + k * 256 + t];
  __syncthreads();
  int px = st * 256 + t;
  const float* rb = res + (size_t)b * 524288 + px;
  float acc[16];
#pragma unroll
  for (int r = 0; r < 16; r++) acc[r] = 0.f;
  for (int ci = 0; ci < 128; ci += 4) {
    float xv[4];
#pragma unroll
    for (int kk = 0; kk < 4; kk++) xv[kk] = rb[(size_t)(ci + kk) * HW];
#pragma unroll
    for (int r = 0; r < 16; r++) {
      floatx4 wv = *(const floatx4*)&wt[r * 128 + ci];
#pragma unroll
      for (int kk = 0; kk < 4; kk++) acc[r] += wv[kk] * xv[kk];
    }
  }
  const float* xb = x + ((size_t)b * 256 + co0) * HW + px;
  float* ob = out + ((size_t)b * 256 + co0) * HW + px;
#pragma unroll
  for (int r = 0; r < 16; r++) {
    int co = co0 + r;
    float g = gamma[co] * rsqrtf(rvar[co] + 1e-5f);
    float bb = beta[co] - rmean[co] * g;
    ob[(size_t)r * HW] = acc[r] * g + bb + xb[(size_t)r * HW];
  }
}

extern "C" void kernel_launch(void* const* d_in, const int* in_sizes, int n_in,
                              void* d_out, int out_size, void* d_ws, size_t ws_size,
                              hipStream_t stream) {
  const float* x     = (const float*)d_in[0];
  const float* w1    = (const float*)d_in[1];
  const float* w2    = (const float*)d_in[2];
  const float* w3    = (const float*)d_in[3];
  const float* w4    = (const float*)d_in[4];
  const float* gamma = (const float*)d_in[5];
  const float* beta  = (const float*)d_in[6];
  const float* rmean = (const float*)d_in[7];
  const float* rvar  = (const float*)d_in[8];
  float* out = (float*)d_out;
  char* ws = (char*)d_ws;

  // Opart region (32 MB) overlaps n3 / Xth / Xtl (all dead before k_flash runs)
  size_t off = (size_t)SPLIT * 4 * HW * 128 * 4;             // 32 MB
  float* Opart = (float*)ws;
  unsigned short* n3  = (unsigned short*)ws;                  // 4.2 MB @ 0
  unsigned short* Xth = (unsigned short*)(ws + ((size_t)8  << 20));  // 8.4 MB @ 8M
  unsigned short* Xtl = (unsigned short*)(ws + ((size_t)17 << 20));  // 8.4 MB @ 17M
  unsigned short* Q  = (unsigned short*)(ws + off); off += (size_t)4 * HW * 128 * 2;
  unsigned short* Kt = (unsigned short*)(ws + off); off += (size_t)4 * HW * 128 * 2;
  unsigned short* Vt = (unsigned short*)(ws + off); off += (size_t)4 * HW * 128 * 2;
  float* ml  = (float*)(ws + off); off += (size_t)SPLIT * 4 * HW * 2 * 4;
  float* res = (float*)(ws + off); off += (size_t)4 * HW * 128 * 4;
  unsigned short* Wh = (unsigned short*)(ws + off); off += (size_t)384 * 256 * 2;
  unsigned short* Wl = (unsigned short*)(ws + off); off += (size_t)384 * 256 * 2;
  if (ws_size < off) return;  // insufficient workspace: bail (validation will flag)

  k_split  <<<1036, 256, 0, stream>>>(x, w1, w2, w3, Xth, Xtl, Wh, Wl);
  k_projM  <<<768,  256, 0, stream>>>(Xth, Xtl, Wh, Wl, Q, Kt, n3);
  k_layoutV<<<256,  256, 0, stream>>>(n3, Vt);
  k_flash  <<<1024, 256, 0, stream>>>(Q, Kt, Vt, Opart, ml);
  k_merge  <<<2048, 256, 0, stream>>>(Opart, ml, res);
  k_out    <<<1024, 256, 0, stream>>>(res, w4, gamma, beta, rmean, rvar, x, out);
}

// Round 6
// 210.893 us; speedup vs baseline: 1.7107x; 1.0651x over previous
//
#include <hip/hip_runtime.h>
#include <cstdint>

#define BN 4
#define CIN 256
#define HALFC 128
#define HW 4096
#define SPLIT 4
#define JT 64
#define JITERS (HW / SPLIT / JT)   // 16

typedef float  floatx4 __attribute__((ext_vector_type(4)));
typedef short  shortx8 __attribute__((ext_vector_type(8)));

#if __has_builtin(__builtin_amdgcn_exp2f)
#define EXP2F(x) __builtin_amdgcn_exp2f(x)
#else
#define EXP2F(x) exp2f(x)
#endif
#define L2E 1.44269504088896f

__device__ __forceinline__ unsigned short f2bf(float f) {
  unsigned u = __float_as_uint(f);
  u += 0x7FFFu + ((u >> 16) & 1u);   // round-to-nearest-even
  return (unsigned short)(u >> 16);
}
__device__ __forceinline__ float bf2f(unsigned short h) {
  return __uint_as_float((unsigned)h << 16);
}

__device__ __forceinline__ void async16(const void* g, void* l) {
  __builtin_amdgcn_global_load_lds((const __attribute__((address_space(1))) void*)g,
                                   (__attribute__((address_space(3))) void*)l, 16, 0, 0);
}

// ---------------- K0: split x -> Xt (transposed [b][px][ci], bf16 hi/lo); W -> Wh/Wl ---
__global__ __launch_bounds__(256) void k_split(const float* __restrict__ x,
    const float* __restrict__ w1, const float* __restrict__ w2,
    const float* __restrict__ w3, unsigned short* __restrict__ Xth,
    unsigned short* __restrict__ Xtl, unsigned short* __restrict__ Wh,
    unsigned short* __restrict__ Wl) {
  __shared__ float smf[64 * 65];
  int bid = blockIdx.x;
  int t = threadIdx.x;
  if (bid < 1024) {
    int b = bid >> 8, rem = bid & 255;
    int cit = rem >> 6, pxt = rem & 63;     // ci tile (4), px tile (64)
    const float* src = x + (size_t)b * 1048576 + (size_t)(cit * 64) * HW + pxt * 64;
#pragma unroll
    for (int k = 0; k < 16; k++) {
      int idx = k * 256 + t;
      int r = idx >> 6, c = idx & 63;
      smf[r * 65 + c] = src[(size_t)r * HW + c];
    }
    __syncthreads();
    int prow = t >> 2, seg = t & 3;
    union { unsigned short us[16]; uint4 v[2]; } oh, ol;
#pragma unroll
    for (int u = 0; u < 16; u++) {
      float v = smf[(seg * 16 + u) * 65 + prow];
      unsigned short hh = f2bf(v);
      oh.us[u] = hh;
      ol.us[u] = f2bf(v - bf2f(hh));
    }
    size_t dst = (size_t)b * 1048576 + (size_t)(pxt * 64 + prow) * 256 + cit * 64 + seg * 16;
    *(uint4*)(Xth + dst) = oh.v[0];
    *(uint4*)(Xth + dst + 8) = oh.v[1];
    *(uint4*)(Xtl + dst) = ol.v[0];
    *(uint4*)(Xtl + dst + 8) = ol.v[1];
  } else {
    int bw = bid - 1024;                    // 0..11, each block 8192 elems
    int f0 = bw * 8192 + t * 32;
    const float* wsrc;
    int fo;
    if (f0 < 32768)      { wsrc = w1; fo = f0; }
    else if (f0 < 65536) { wsrc = w2; fo = f0 - 32768; }
    else                 { wsrc = w3; fo = f0 - 65536; }
    union { unsigned short us[32]; uint4 v[4]; } oh, ol;
#pragma unroll
    for (int u = 0; u < 32; u++) {
      float v = wsrc[fo + u];
      unsigned short hh = f2bf(v);
      oh.us[u] = hh;
      ol.us[u] = f2bf(v - bf2f(hh));
    }
#pragma unroll
    for (int k = 0; k < 4; k++) {
      *((uint4*)(Wh + f0) + k) = oh.v[k];
      *((uint4*)(Wl + f0) + k) = ol.v[k];
    }
  }
}

// ---------------- K1: MFMA projection (bf16-split, fp32 acc) ---------------------------
__global__ __launch_bounds__(256) void k_projM(const unsigned short* __restrict__ Xth,
    const unsigned short* __restrict__ Xtl, const unsigned short* __restrict__ Wh,
    const unsigned short* __restrict__ Wl, unsigned short* __restrict__ Q,
    unsigned short* __restrict__ Kt, unsigned short* __restrict__ n3) {
  __shared__ unsigned short XhS[4096];   // [128 px][32 ci] in fragment order, 8 KB
  __shared__ unsigned short XlS[4096];
  __shared__ unsigned short ES[9216];    // epilogue stage
  int bid = blockIdx.x;
  int pxt = bid & 31;
  int ct = bid >> 5;                     // b*6 + cot
  int b = ct / 6, cot = ct % 6;
  int px0 = pxt * 128, co0 = cot * 64;
  int t = threadIdx.x;
  int w = t >> 6, lane = t & 63, l16 = lane & 15, quad = lane >> 4;

  // preload W fragments (B-operand): lane: co = co0+w*16+l16, k = s*32+quad*8+j
  int myco = co0 + w * 16 + l16;
  shortx8 whf[8], wlf[8];
#pragma unroll
  for (int s = 0; s < 8; s++) {
    whf[s] = *(const shortx8*)(Wh + (size_t)myco * 256 + s * 32 + quad * 8);
    wlf[s] = *(const shortx8*)(Wl + (size_t)myco * 256 + s * 32 + quad * 8);
  }
  floatx4 acc[8];
  floatx4 zf = {0.f, 0.f, 0.f, 0.f};
#pragma unroll
  for (int mt = 0; mt < 8; mt++) acc[mt] = zf;
  const unsigned short* XhB = Xth + (size_t)b * 1048576;
  const unsigned short* XlB = Xtl + (size_t)b * 1048576;
  int k8 = lane >> 4, pxm = lane & 15;

#pragma unroll
  for (int s = 0; s < 8; s++) {
    __syncthreads();
#pragma unroll
    for (int c2 = 0; c2 < 2; c2++) {     // stage fragment-order; lane L -> slot L*16
      int px = px0 + (c2 * 4 + w) * 16 + pxm;
      size_t so = (size_t)px * 256 + s * 32 + k8 * 8;
      async16(XhB + so, (char*)XhS + c2 * 4096 + w * 1024);
      async16(XlB + so, (char*)XlS + c2 * 4096 + w * 1024);
    }
    __syncthreads();
#pragma unroll
    for (int mt = 0; mt < 8; mt++) {
      shortx8 ah = *(const shortx8*)((const char*)XhS + mt * 1024 + lane * 16);
      shortx8 al = *(const shortx8*)((const char*)XlS + mt * 1024 + lane * 16);
      acc[mt] = __builtin_amdgcn_mfma_f32_16x16x32_bf16(ah, whf[s], acc[mt], 0, 0, 0);
      acc[mt] = __builtin_amdgcn_mfma_f32_16x16x32_bf16(al, whf[s], acc[mt], 0, 0, 0);
      acc[mt] = __builtin_amdgcn_mfma_f32_16x16x32_bf16(ah, wlf[s], acc[mt], 0, 0, 0);
    }
  }
  __syncthreads();
  // D layout: element [px = mt*16 + quad*4 + rr][co_l = w*16 + l16]
  if (cot < 2 || cot >= 4) {             // Q / n3: need [co][px] rows -> stage [co][px]
    int co_l = w * 16 + l16;
#pragma unroll
    for (int mt = 0; mt < 8; mt++) {
      int px = mt * 16 + quad * 4;
      unsigned lo = (unsigned)f2bf(acc[mt][0]) | ((unsigned)f2bf(acc[mt][1]) << 16);
      unsigned hi = (unsigned)f2bf(acc[mt][2]) | ((unsigned)f2bf(acc[mt][3]) << 16);
      *(uint2*)(ES + co_l * 136 + px) = make_uint2(lo, hi);
    }
    __syncthreads();
    int cr = t >> 2, seg = t & 3;
    unsigned short* dstb = (cot < 2)
        ? Q  + (size_t)b * 524288 + (size_t)(co0 + cr) * HW
        : n3 + (size_t)b * 524288 + (size_t)(co0 - 256 + cr) * HW;
#pragma unroll
    for (int k2 = 0; k2 < 4; k2++) {
      uint4 v = *(const uint4*)(ES + cr * 136 + seg * 32 + k2 * 8);
      *(uint4*)(dstb + px0 + seg * 32 + k2 * 8) = v;
    }
  } else {                               // Kt: need [px][ch'] rows -> stage [px][co]
#pragma unroll
    for (int mt = 0; mt < 8; mt++)
#pragma unroll
      for (int rr = 0; rr < 4; rr++) {
        int px = mt * 16 + quad * 4 + rr;
        ES[px * 72 + w * 16 + l16] = f2bf(acc[mt][rr]);
      }
    __syncthreads();
    int ch0 = co0 - 128;
#pragma unroll
    for (int it = 0; it < 4; it++) {
      int cid = it * 256 + t;
      int px = cid >> 3, c8 = cid & 7;
      uint4 v = *(const uint4*)(ES + px * 72 + c8 * 8);
      *(uint4*)(Kt + (size_t)b * 524288 + (size_t)(px0 + px) * 128 + ch0 + c8 * 8) = v;
    }
  }
}

// ---------------- K2: Vt shuffle: Vt[b][c][j] = n3[j>>5][((j&31)<<7)+c] ---------------
__global__ __launch_bounds__(256) void k_layoutV(const unsigned short* __restrict__ n3,
    unsigned short* __restrict__ Vt) {
  __shared__ unsigned short sm[8192];
  int bid = blockIdx.x;
  int t = threadIdx.x;
  int b = bid >> 6;
  int chg = bid & 63;
  const unsigned short* src = n3 + (size_t)b * 524288 + (size_t)(chg * 2) * HW;
#pragma unroll
  for (int k = 0; k < 32; k++) {
    int idx = k * 256 + t;
    sm[idx] = src[idx];
  }
  __syncthreads();
  int c = t >> 1, half = t & 1;
  union { unsigned short us[32]; uint4 v[4]; } o;
#pragma unroll
  for (int u = 0; u < 32; u++) o.us[u] = sm[half * 4096 + u * 128 + c];
  unsigned short* d = Vt + ((size_t)b * 128 + c) * HW + chg * 64 + half * 32;
#pragma unroll
  for (int k = 0; k < 4; k++) *((uint4*)d + k) = o.v[k];
}

// ---------------- K3: fused flash attention (bf16 MFMA, split-j) -----------------------
// Wave owns 32 i (2 groups of 16). LDS tiles in fragment order (lane-linear reads);
// each Kt/Vt fragment read feeds 2 MFMAs (halved LDS read amplification vs 16-i).
// grid: 512 = b(4) x sp(4) x itile(32); block 256 (4 waves).
__global__ __launch_bounds__(256, 2) void k_flash(const unsigned short* __restrict__ Q,
    const unsigned short* __restrict__ Kt, const unsigned short* __restrict__ Vt,
    float* __restrict__ Opart, float* __restrict__ ml) {
  __shared__ unsigned short KtS[64 * 128];   // 16 KB
  __shared__ unsigned short VtS[128 * 64];   // 16 KB
  __shared__ unsigned short PS[4 * 32 * 64]; // 16 KB (4 KB per wave)
  int bid = blockIdx.x;
  int itile = bid & 31, sp = (bid >> 5) & 3, b = bid >> 7;
  int t = threadIdx.x;
  int w = t >> 6, lane = t & 63, l16 = lane & 15, quad = lane >> 4;
  int i0 = itile * 128;

  shortx8 qf[2][4];   // B-frags of Q for this wave's 2x16 i
#pragma unroll
  for (int ig = 0; ig < 2; ig++) {
    const unsigned short* qp = Q + ((size_t)b * HW + i0 + w * 32 + ig * 16 + l16) * 128 + quad * 8;
#pragma unroll
    for (int ks = 0; ks < 4; ks++) qf[ig][ks] = *(const shortx8*)(qp + ks * 32);
  }
  floatx4 O[2][8];
  floatx4 zf = {0.f, 0.f, 0.f, 0.f};
#pragma unroll
  for (int ig = 0; ig < 2; ig++)
#pragma unroll
    for (int nt = 0; nt < 8; nt++) O[ig][nt] = zf;
  float m_i[2] = {-1e30f, -1e30f}, l_i[2] = {0.f, 0.f};

  // hoisted staging pointers (advance by constant stride per iter)
  int ccK = w * 4 + (lane >> 4);
  const unsigned short* kbase = Kt + (size_t)b * HW * 128
                              + (size_t)(sp * 1024 + l16) * 128 + ccK * 8;
  int ccV = (w & 1) * 4 + (lane >> 4);
  const unsigned short* vbase = Vt + ((size_t)b * 128 + (w >> 1) * 16 + l16) * HW
                              + sp * 1024 + ccV * 8;
  char* Pw = (char*)PS + w * 4096;

  for (int it = 0; it < JITERS; it++) {
    __syncthreads();                       // previous tile fully consumed
#pragma unroll
    for (int c4 = 0; c4 < 4; c4++)         // stage Kt: frag-order, lane-linear
      async16(kbase + (size_t)it * 8192 + c4 * 2048, (char*)KtS + c4 * 4096 + w * 1024);
#pragma unroll
    for (int c4 = 0; c4 < 4; c4++)         // stage Vt
      async16(vbase + (size_t)c4 * 32 * HW + it * 64, (char*)VtS + c4 * 4096 + w * 1024);
    __syncthreads();                       // vmcnt drain + barrier

    // ---- QK: S^T[j][i]; each af feeds both i-groups ----
    floatx4 S[2][4];
#pragma unroll
    for (int ig = 0; ig < 2; ig++)
#pragma unroll
      for (int mt = 0; mt < 4; mt++) S[ig][mt] = zf;
#pragma unroll
    for (int mt = 0; mt < 4; mt++) {
#pragma unroll
      for (int ks = 0; ks < 4; ks++) {
        shortx8 af = *(const shortx8*)((const char*)KtS + mt * 4096 + ks * 1024 + lane * 16);
        S[0][mt] = __builtin_amdgcn_mfma_f32_16x16x32_bf16(af, qf[0][ks], S[0][mt], 0, 0, 0);
        S[1][mt] = __builtin_amdgcn_mfma_f32_16x16x32_bf16(af, qf[1][ks], S[1][mt], 0, 0, 0);
      }
    }
    // ---- online softmax over j, per i-group; P overwrites S ----
    float alpha[2];
#pragma unroll
    for (int ig = 0; ig < 2; ig++) {
      float tmax = S[ig][0][0];
#pragma unroll
      for (int mt = 0; mt < 4; mt++)
#pragma unroll
        for (int rr = 0; rr < 4; rr++) tmax = fmaxf(tmax, S[ig][mt][rr]);
      tmax = fmaxf(tmax, __shfl_xor(tmax, 16));
      tmax = fmaxf(tmax, __shfl_xor(tmax, 32));
      float mnew = fmaxf(m_i[ig], tmax);
      alpha[ig] = EXP2F((m_i[ig] - mnew) * L2E);
      float tsum = 0.f;
#pragma unroll
      for (int mt = 0; mt < 4; mt++)
#pragma unroll
        for (int rr = 0; rr < 4; rr++) {
          float p = EXP2F((S[ig][mt][rr] - mnew) * L2E);
          S[ig][mt][rr] = p;
          tsum += p;
        }
      tsum += __shfl_xor(tsum, 16);
      tsum += __shfl_xor(tsum, 32);
      l_i[ig] = l_i[ig] * alpha[ig] + tsum;
      m_i[ig] = mnew;
    }
    // O rescale: row i_local = quad*4+rr; alpha lives at lane with l16 == i_local
#pragma unroll
    for (int ig = 0; ig < 2; ig++) {
      float ar[4];
#pragma unroll
      for (int rr = 0; rr < 4; rr++) ar[rr] = __shfl(alpha[ig], quad * 4 + rr);
#pragma unroll
      for (int nt = 0; nt < 8; nt++)
#pragma unroll
        for (int rr = 0; rr < 4; rr++) O[ig][nt][rr] *= ar[rr];
    }
    // ---- P -> wave-private LDS (C-layout -> A-frag order) ----
#pragma unroll
    for (int ig = 0; ig < 2; ig++)
#pragma unroll
      for (int mt = 0; mt < 4; mt++) {
        unsigned lo = (unsigned)f2bf(S[ig][mt][0]) | ((unsigned)f2bf(S[ig][mt][1]) << 16);
        unsigned hi = (unsigned)f2bf(S[ig][mt][2]) | ((unsigned)f2bf(S[ig][mt][3]) << 16);
        *(uint2*)(Pw + ig * 2048 + (mt * 2 + (quad >> 1)) * 256 + l16 * 16 + (quad & 1) * 8)
            = make_uint2(lo, hi);
      }
    __threadfence_block();                 // intra-wave LDS write->read ordering
    // ---- PV: O[i][c] += P[i][j] * V[j][c]; each vf feeds both i-groups ----
#pragma unroll
    for (int kt = 0; kt < 2; kt++) {
      shortx8 pf0 = *(const shortx8*)(Pw + kt * 1024 + lane * 16);
      shortx8 pf1 = *(const shortx8*)(Pw + 2048 + kt * 1024 + lane * 16);
#pragma unroll
      for (int nt = 0; nt < 8; nt++) {
        shortx8 vf = *(const shortx8*)((const char*)VtS + nt * 2048 + kt * 1024 + lane * 16);
        O[0][nt] = __builtin_amdgcn_mfma_f32_16x16x32_bf16(pf0, vf, O[0][nt], 0, 0, 0);
        O[1][nt] = __builtin_amdgcn_mfma_f32_16x16x32_bf16(pf1, vf, O[1][nt], 0, 0, 0);
      }
    }
  }
  // epilogue: store partial O and (m,l)
#pragma unroll
  for (int ig = 0; ig < 2; ig++) {
    float* Ob = Opart + ((size_t)(sp * 4 + b) * HW + i0 + w * 32 + ig * 16) * 128;
#pragma unroll
    for (int nt = 0; nt < 8; nt++)
#pragma unroll
      for (int rr = 0; rr < 4; rr++)
        Ob[(size_t)(quad * 4 + rr) * 128 + nt * 16 + l16] = O[ig][nt][rr];
  }
  if (quad == 0) {
    float2* mlp = (float2*)ml;
#pragma unroll
    for (int ig = 0; ig < 2; ig++)
      mlp[(size_t)(sp * 4 + b) * HW + i0 + w * 32 + ig * 16 + l16]
          = make_float2(m_i[ig], l_i[ig]);
  }
}

// ---------------- K4: merge split-j partials -> res (flat == resmap layout) -----------
__global__ __launch_bounds__(256) void k_merge(const float* __restrict__ Opart,
    const float* __restrict__ ml, float* __restrict__ res) {
  size_t e = (size_t)blockIdx.x * 256 + threadIdx.x;  // float4 index
  int cq = (int)(e & 31);
  int i = (int)((e >> 5) & 4095);
  int b = (int)(e >> 17);
  const float2* mlp = (const float2*)ml;
  float m[SPLIT], l[SPLIT];
  float M = -1e30f;
#pragma unroll
  for (int s = 0; s < SPLIT; s++) {
    float2 st = mlp[(size_t)(s * 4 + b) * HW + i];
    m[s] = st.x; l[s] = st.y;
    M = fmaxf(M, m[s]);
  }
  float denom = 0.f;
  float wgt[SPLIT];
#pragma unroll
  for (int s = 0; s < SPLIT; s++) {
    float ws_ = EXP2F((m[s] - M) * L2E);
    wgt[s] = ws_;
    denom += l[s] * ws_;
  }
  float inv = 1.f / denom;
  floatx4 acc = {0.f, 0.f, 0.f, 0.f};
#pragma unroll
  for (int s = 0; s < SPLIT; s++) {
    floatx4 v = *(const floatx4*)(Opart + ((size_t)(s * 4 + b) * HW + i) * 128 + cq * 4);
    acc += v * (wgt[s] * inv);
  }
  *(floatx4*)(res + e * 4) = acc;
}

// ---------------- K5: conv4 (fp32) + BN(eval) + residual ------------------------------
// grid 1024 = b(4) x st(16) x cot(16); thread: 16 co x 1 px.
__global__ __launch_bounds__(256) void k_out(const float* __restrict__ res,
    const float* __restrict__ w4, const float* __restrict__ gamma,
    const float* __restrict__ beta, const float* __restrict__ rmean,
    const float* __restrict__ rvar, const float* __restrict__ x,
    float* __restrict__ out) {
  __shared__ float wt[16 * 128];
  int bid = blockIdx.x;
  int cot = bid & 15;
  int st = (bid >> 4) & 15;
  int b = bid >> 8;
  int t = threadIdx.x;
  int co0 = cot * 16;
#pragma unroll
  for (int k = 0; k < 8; k++) wt[k * 256 + t] = w4[(size_t)co0 * 128 + k * 256 + t];
  __syncthreads();
  int px = st * 256 + t;
  const float* rb = res + (size_t)b * 524288 + px;
  float acc[16];
#pragma unroll
  for (int r = 0; r < 16; r++) acc[r] = 0.f;
  for (int ci = 0; ci < 128; ci += 4) {
    float xv[4];
#pragma unroll
    for (int kk = 0; kk < 4; kk++) xv[kk] = rb[(size_t)(ci + kk) * HW];
#pragma unroll
    for (int r = 0; r < 16; r++) {
      floatx4 wv = *(const floatx4*)&wt[r * 128 + ci];
#pragma unroll
      for (int kk = 0; kk < 4; kk++) acc[r] += wv[kk] * xv[kk];
    }
  }
  const float* xb = x + ((size_t)b * 256 + co0) * HW + px;
  float* ob = out + ((size_t)b * 256 + co0) * HW + px;
#pragma unroll
  for (int r = 0; r < 16; r++) {
    int co = co0 + r;
    float g = gamma[co] * rsqrtf(rvar[co] + 1e-5f);
    float bb = beta[co] - rmean[co] * g;
    ob[(size_t)r * HW] = acc[r] * g + bb + xb[(size_t)r * HW];
  }
}

extern "C" void kernel_launch(void* const* d_in, const int* in_sizes, int n_in,
                              void* d_out, int out_size, void* d_ws, size_t ws_size,
                              hipStream_t stream) {
  const float* x     = (const float*)d_in[0];
  const float* w1    = (const float*)d_in[1];
  const float* w2    = (const float*)d_in[2];
  const float* w3    = (const float*)d_in[3];
  const float* w4    = (const float*)d_in[4];
  const float* gamma = (const float*)d_in[5];
  const float* beta  = (const float*)d_in[6];
  const float* rmean = (const float*)d_in[7];
  const float* rvar  = (const float*)d_in[8];
  float* out = (float*)d_out;
  char* ws = (char*)d_ws;

  // Opart region (32 MB) overlaps n3 / Xth / Xtl (all dead before k_flash runs)
  size_t off = (size_t)SPLIT * 4 * HW * 128 * 4;             // 32 MB
  float* Opart = (float*)ws;
  unsigned short* n3  = (unsigned short*)ws;                  // 4.2 MB @ 0
  unsigned short* Xth = (unsigned short*)(ws + ((size_t)8  << 20));  // 8.4 MB @ 8M
  unsigned short* Xtl = (unsigned short*)(ws + ((size_t)17 << 20));  // 8.4 MB @ 17M
  unsigned short* Q  = (unsigned short*)(ws + off); off += (size_t)4 * HW * 128 * 2;
  unsigned short* Kt = (unsigned short*)(ws + off); off += (size_t)4 * HW * 128 * 2;
  unsigned short* Vt = (unsigned short*)(ws + off); off += (size_t)4 * HW * 128 * 2;
  float* ml  = (float*)(ws + off); off += (size_t)SPLIT * 4 * HW * 2 * 4;
  float* res = (float*)(ws + off); off += (size_t)4 * HW * 128 * 4;
  unsigned short* Wh = (unsigned short*)(ws + off); off += (size_t)384 * 256 * 2;
  unsigned short* Wl = (unsigned short*)(ws + off); off += (size_t)384 * 256 * 2;
  if (ws_size < off) return;  // insufficient workspace: bail (validation will flag)

  k_split  <<<1036, 256, 0, stream>>>(x, w1, w2, w3, Xth, Xtl, Wh, Wl);
  k_projM  <<<768,  256, 0, stream>>>(Xth, Xtl, Wh, Wl, Q, Kt, n3);
  k_layoutV<<<256,  256, 0, stream>>>(n3, Vt);
  k_flash  <<<512,  256, 0, stream>>>(Q, Kt, Vt, Opart, ml);
  k_merge  <<<2048, 256, 0, stream>>>(Opart, ml, res);
  k_out    <<<1024, 256, 0, stream>>>(res, w4, gamma, beta, rmean, rvar, x, out);
}

// Round 8
// 209.188 us; speedup vs baseline: 1.7247x; 1.0082x over previous
//
#include <hip/hip_runtime.h>
#include <cstdint>

#define BN 4
#define CIN 256
#define HALFC 128
#define HW 4096
#define SPLIT 4
#define JT 64
#define JITERS (HW / SPLIT / JT)   // 16

typedef float  floatx4 __attribute__((ext_vector_type(4)));
typedef short  shortx8 __attribute__((ext_vector_type(8)));

#if __has_builtin(__builtin_amdgcn_exp2f)
#define EXP2F(x) __builtin_amdgcn_exp2f(x)
#else
#define EXP2F(x) exp2f(x)
#endif
#define L2E 1.44269504088896f

__device__ __forceinline__ unsigned short f2bf(float f) {
  unsigned u = __float_as_uint(f);
  u += 0x7FFFu + ((u >> 16) & 1u);   // round-to-nearest-even
  return (unsigned short)(u >> 16);
}
__device__ __forceinline__ float bf2f(unsigned short h) {
  return __uint_as_float((unsigned)h << 16);
}

__device__ __forceinline__ void async16(const void* g, void* l) {
  __builtin_amdgcn_global_load_lds((const __attribute__((address_space(1))) void*)g,
                                   (__attribute__((address_space(3))) void*)l, 16, 0, 0);
}

// ---------------- K0: split x -> Xt (transposed [b][px][ci], bf16 hi/lo); W -> Wh/Wl ---
__global__ __launch_bounds__(256) void k_split(const float* __restrict__ x,
    const float* __restrict__ w1, const float* __restrict__ w2,
    const float* __restrict__ w3, unsigned short* __restrict__ Xth,
    unsigned short* __restrict__ Xtl, unsigned short* __restrict__ Wh,
    unsigned short* __restrict__ Wl) {
  __shared__ float smf[64 * 65];
  int bid = blockIdx.x;
  int t = threadIdx.x;
  if (bid < 1024) {
    int b = bid >> 8, rem = bid & 255;
    int cit = rem >> 6, pxt = rem & 63;     // ci tile (4), px tile (64)
    const float* src = x + (size_t)b * 1048576 + (size_t)(cit * 64) * HW + pxt * 64;
#pragma unroll
    for (int k = 0; k < 16; k++) {
      int idx = k * 256 + t;
      int r = idx >> 6, c = idx & 63;
      smf[r * 65 + c] = src[(size_t)r * HW + c];
    }
    __syncthreads();
    int prow = t >> 2, seg = t & 3;
    union { unsigned short us[16]; uint4 v[2]; } oh, ol;
#pragma unroll
    for (int u = 0; u < 16; u++) {
      float v = smf[(seg * 16 + u) * 65 + prow];
      unsigned short hh = f2bf(v);
      oh.us[u] = hh;
      ol.us[u] = f2bf(v - bf2f(hh));
    }
    size_t dst = (size_t)b * 1048576 + (size_t)(pxt * 64 + prow) * 256 + cit * 64 + seg * 16;
    *(uint4*)(Xth + dst) = oh.v[0];
    *(uint4*)(Xth + dst + 8) = oh.v[1];
    *(uint4*)(Xtl + dst) = ol.v[0];
    *(uint4*)(Xtl + dst + 8) = ol.v[1];
  } else {
    int bw = bid - 1024;                    // 0..11, each block 8192 elems
    int f0 = bw * 8192 + t * 32;
    const float* wsrc;
    int fo;
    if (f0 < 32768)      { wsrc = w1; fo = f0; }
    else if (f0 < 65536) { wsrc = w2; fo = f0 - 32768; }
    else                 { wsrc = w3; fo = f0 - 65536; }
    union { unsigned short us[32]; uint4 v[4]; } oh, ol;
#pragma unroll
    for (int u = 0; u < 32; u++) {
      float v = wsrc[fo + u];
      unsigned short hh = f2bf(v);
      oh.us[u] = hh;
      ol.us[u] = f2bf(v - bf2f(hh));
    }
#pragma unroll
    for (int k = 0; k < 4; k++) {
      *((uint4*)(Wh + f0) + k) = oh.v[k];
      *((uint4*)(Wl + f0) + k) = ol.v[k];
    }
  }
}

// ---------------- K1: MFMA projection (bf16-split, fp32 acc) ---------------------------
__global__ __launch_bounds__(256) void k_projM(const unsigned short* __restrict__ Xth,
    const unsigned short* __restrict__ Xtl, const unsigned short* __restrict__ Wh,
    const unsigned short* __restrict__ Wl, unsigned short* __restrict__ Q,
    unsigned short* __restrict__ Kt, unsigned short* __restrict__ n3) {
  __shared__ unsigned short XhS[4096];   // [128 px][32 ci] in fragment order, 8 KB
  __shared__ unsigned short XlS[4096];
  __shared__ unsigned short ES[9216];    // epilogue stage
  int bid = blockIdx.x;
  int pxt = bid & 31;
  int ct = bid >> 5;                     // b*6 + cot
  int b = ct / 6, cot = ct % 6;
  int px0 = pxt * 128, co0 = cot * 64;
  int t = threadIdx.x;
  int w = t >> 6, lane = t & 63, l16 = lane & 15, quad = lane >> 4;

  // preload W fragments (B-operand): lane: co = co0+w*16+l16, k = s*32+quad*8+j
  int myco = co0 + w * 16 + l16;
  shortx8 whf[8], wlf[8];
#pragma unroll
  for (int s = 0; s < 8; s++) {
    whf[s] = *(const shortx8*)(Wh + (size_t)myco * 256 + s * 32 + quad * 8);
    wlf[s] = *(const shortx8*)(Wl + (size_t)myco * 256 + s * 32 + quad * 8);
  }
  floatx4 acc[8];
  floatx4 zf = {0.f, 0.f, 0.f, 0.f};
#pragma unroll
  for (int mt = 0; mt < 8; mt++) acc[mt] = zf;
  const unsigned short* XhB = Xth + (size_t)b * 1048576;
  const unsigned short* XlB = Xtl + (size_t)b * 1048576;
  int k8 = lane >> 4, pxm = lane & 15;

#pragma unroll
  for (int s = 0; s < 8; s++) {
    __syncthreads();
#pragma unroll
    for (int c2 = 0; c2 < 2; c2++) {     // stage fragment-order; lane L -> slot L*16
      int px = px0 + (c2 * 4 + w) * 16 + pxm;
      size_t so = (size_t)px * 256 + s * 32 + k8 * 8;
      async16(XhB + so, (char*)XhS + c2 * 4096 + w * 1024);
      async16(XlB + so, (char*)XlS + c2 * 4096 + w * 1024);
    }
    __syncthreads();
#pragma unroll
    for (int mt = 0; mt < 8; mt++) {
      shortx8 ah = *(const shortx8*)((const char*)XhS + mt * 1024 + lane * 16);
      shortx8 al = *(const shortx8*)((const char*)XlS + mt * 1024 + lane * 16);
      acc[mt] = __builtin_amdgcn_mfma_f32_16x16x32_bf16(ah, whf[s], acc[mt], 0, 0, 0);
      acc[mt] = __builtin_amdgcn_mfma_f32_16x16x32_bf16(al, whf[s], acc[mt], 0, 0, 0);
      acc[mt] = __builtin_amdgcn_mfma_f32_16x16x32_bf16(ah, wlf[s], acc[mt], 0, 0, 0);
    }
  }
  __syncthreads();
  // D layout: element [px = mt*16 + quad*4 + rr][co_l = w*16 + l16]
  if (cot < 2 || cot >= 4) {             // Q / n3: need [co][px] rows -> stage [co][px]
    int co_l = w * 16 + l16;
#pragma unroll
    for (int mt = 0; mt < 8; mt++) {
      int px = mt * 16 + quad * 4;
      unsigned lo = (unsigned)f2bf(acc[mt][0]) | ((unsigned)f2bf(acc[mt][1]) << 16);
      unsigned hi = (unsigned)f2bf(acc[mt][2]) | ((unsigned)f2bf(acc[mt][3]) << 16);
      *(uint2*)(ES + co_l * 136 + px) = make_uint2(lo, hi);
    }
    __syncthreads();
    int cr = t >> 2, seg = t & 3;
    unsigned short* dstb = (cot < 2)
        ? Q  + (size_t)b * 524288 + (size_t)(co0 + cr) * HW
        : n3 + (size_t)b * 524288 + (size_t)(co0 - 256 + cr) * HW;
#pragma unroll
    for (int k2 = 0; k2 < 4; k2++) {
      uint4 v = *(const uint4*)(ES + cr * 136 + seg * 32 + k2 * 8);
      *(uint4*)(dstb + px0 + seg * 32 + k2 * 8) = v;
    }
  } else {                               // Kt: need [px][ch'] rows -> stage [px][co]
#pragma unroll
    for (int mt = 0; mt < 8; mt++)
#pragma unroll
      for (int rr = 0; rr < 4; rr++) {
        int px = mt * 16 + quad * 4 + rr;
        ES[px * 72 + w * 16 + l16] = f2bf(acc[mt][rr]);
      }
    __syncthreads();
    int ch0 = co0 - 128;
#pragma unroll
    for (int it = 0; it < 4; it++) {
      int cid = it * 256 + t;
      int px = cid >> 3, c8 = cid & 7;
      uint4 v = *(const uint4*)(ES + px * 72 + c8 * 8);
      *(uint4*)(Kt + (size_t)b * 524288 + (size_t)(px0 + px) * 128 + ch0 + c8 * 8) = v;
    }
  }
}

// ---------------- K2: Vt shuffle: Vt[b][c][j] = n3[j>>5][((j&31)<<7)+c] ---------------
__global__ __launch_bounds__(256) void k_layoutV(const unsigned short* __restrict__ n3,
    unsigned short* __restrict__ Vt) {
  __shared__ unsigned short sm[8192];
  int bid = blockIdx.x;
  int t = threadIdx.x;
  int b = bid >> 6;
  int chg = bid & 63;
  const unsigned short* src = n3 + (size_t)b * 524288 + (size_t)(chg * 2) * HW;
#pragma unroll
  for (int k = 0; k < 32; k++) {
    int idx = k * 256 + t;
    sm[idx] = src[idx];
  }
  __syncthreads();
  int c = t >> 1, half = t & 1;
  union { unsigned short us[32]; uint4 v[4]; } o;
#pragma unroll
  for (int u = 0; u < 32; u++) o.us[u] = sm[half * 4096 + u * 128 + c];
  unsigned short* d = Vt + ((size_t)b * 128 + c) * HW + chg * 64 + half * 32;
#pragma unroll
  for (int k = 0; k < 4; k++) *((uint4*)d + k) = o.v[k];
}

// ---------------- K3: fused flash attention (bf16 MFMA, split-j, dbuf pipeline) --------
// Wave owns 32 i. LDS tiles fragment-order (lane-linear). Double-buffered staging with
// raw s_barrier + fine vmcnt(8): prefetch of tile it+1 stays in flight across compute.
// grid: 512 = b(4) x sp(4) x itile(32); block 256 (4 waves).
__global__ __launch_bounds__(256, 2) void k_flash(const unsigned short* __restrict__ Q,
    const unsigned short* __restrict__ Kt, const unsigned short* __restrict__ Vt,
    float* __restrict__ Opart, float* __restrict__ ml) {
  __shared__ unsigned short KtS[2 * 8192];   // 2 x 16 KB
  __shared__ unsigned short VtS[2 * 8192];   // 2 x 16 KB
  __shared__ unsigned short PS[4 * 32 * 64]; // 16 KB (4 KB per wave)
  int bid = blockIdx.x;
  int itile = bid & 31, sp = (bid >> 5) & 3, b = bid >> 7;
  int t = threadIdx.x;
  int w = t >> 6, lane = t & 63, l16 = lane & 15, quad = lane >> 4;
  int i0 = itile * 128;

  shortx8 qf[2][4];   // B-frags of Q for this wave's 2x16 i
#pragma unroll
  for (int ig = 0; ig < 2; ig++) {
    const unsigned short* qp = Q + ((size_t)b * HW + i0 + w * 32 + ig * 16 + l16) * 128 + quad * 8;
#pragma unroll
    for (int ks = 0; ks < 4; ks++) qf[ig][ks] = *(const shortx8*)(qp + ks * 32);
  }
  // drain Q loads so vmcnt counts below are exactly our async16 batches
  __asm__ __volatile__("s_waitcnt vmcnt(0)" ::: "memory");

  floatx4 O[2][8];
  floatx4 zf = {0.f, 0.f, 0.f, 0.f};
#pragma unroll
  for (int ig = 0; ig < 2; ig++)
#pragma unroll
    for (int nt = 0; nt < 8; nt++) O[ig][nt] = zf;
  float m_i[2] = {-1e30f, -1e30f}, l_i[2] = {0.f, 0.f};

  // hoisted staging pointers (advance by constant stride per iter)
  int ccK = w * 4 + (lane >> 4);
  const unsigned short* kbase = Kt + (size_t)b * HW * 128
                              + (size_t)(sp * 1024 + l16) * 128 + ccK * 8;
  int ccV = (w & 1) * 4 + (lane >> 4);
  const unsigned short* vbase = Vt + ((size_t)b * 128 + (w >> 1) * 16 + l16) * HW
                              + sp * 1024 + ccV * 8;
  char* Pw = (char*)PS + w * 4096;

  // prologue: stage tile 0 into buffer 0 (8 async16 per thread, left in flight)
#pragma unroll
  for (int c4 = 0; c4 < 4; c4++)
    async16(kbase + c4 * 2048, (char*)KtS + c4 * 4096 + w * 1024);
#pragma unroll
  for (int c4 = 0; c4 < 4; c4++)
    async16(vbase + (size_t)c4 * 32 * HW, (char*)VtS + c4 * 4096 + w * 1024);

  for (int it = 0; it < JITERS; it++) {
    int cur = it & 1, nxt = cur ^ 1;
    // barrier A: all waves finished compute(it-1) (which read buf[nxt]) -> safe to overwrite
    __asm__ __volatile__("s_barrier" ::: "memory");
    if (it + 1 < JITERS) {
      const unsigned short* kp = kbase + (size_t)(it + 1) * 8192;
      const unsigned short* vp = vbase + (it + 1) * 64;
#pragma unroll
      for (int c4 = 0; c4 < 4; c4++)
        async16(kp + c4 * 2048, (char*)KtS + nxt * 16384 + c4 * 4096 + w * 1024);
#pragma unroll
      for (int c4 = 0; c4 < 4; c4++)
        async16(vp + (size_t)c4 * 32 * HW, (char*)VtS + nxt * 16384 + c4 * 4096 + w * 1024);
      // wait only for tile it's 8 loads; leave the 8 prefetches in flight
      __asm__ __volatile__("s_waitcnt vmcnt(8)" ::: "memory");
    } else {
      __asm__ __volatile__("s_waitcnt vmcnt(0)" ::: "memory");
    }
    // barrier B: all waves' tile-it loads have landed
    __asm__ __volatile__("s_barrier" ::: "memory");

    const char* kc = (const char*)KtS + cur * 16384;
    const char* vc = (const char*)VtS + cur * 16384;

    // ---- QK: S^T[j][i]; each af feeds both i-groups ----
    floatx4 S[2][4];
#pragma unroll
    for (int ig = 0; ig < 2; ig++)
#pragma unroll
      for (int mt = 0; mt < 4; mt++) S[ig][mt] = zf;
#pragma unroll
    for (int mt = 0; mt < 4; mt++) {
#pragma unroll
      for (int ks = 0; ks < 4; ks++) {
        shortx8 af = *(const shortx8*)(kc + mt * 4096 + ks * 1024 + lane * 16);
        S[0][mt] = __builtin_amdgcn_mfma_f32_16x16x32_bf16(af, qf[0][ks], S[0][mt], 0, 0, 0);
        S[1][mt] = __builtin_amdgcn_mfma_f32_16x16x32_bf16(af, qf[1][ks], S[1][mt], 0, 0, 0);
      }
    }
    // ---- online softmax over j, per i-group; P overwrites S ----
    float alpha[2];
#pragma unroll
    for (int ig = 0; ig < 2; ig++) {
      float tmax = S[ig][0][0];
#pragma unroll
      for (int mt = 0; mt < 4; mt++)
#pragma unroll
        for (int rr = 0; rr < 4; rr++) tmax = fmaxf(tmax, S[ig][mt][rr]);
      tmax = fmaxf(tmax, __shfl_xor(tmax, 16));
      tmax = fmaxf(tmax, __shfl_xor(tmax, 32));
      float mnew = fmaxf(m_i[ig], tmax);
      alpha[ig] = EXP2F((m_i[ig] - mnew) * L2E);
      float tsum = 0.f;
#pragma unroll
      for (int mt = 0; mt < 4; mt++)
#pragma unroll
        for (int rr = 0; rr < 4; rr++) {
          float p = EXP2F((S[ig][mt][rr] - mnew) * L2E);
          S[ig][mt][rr] = p;
          tsum += p;
        }
      tsum += __shfl_xor(tsum, 16);
      tsum += __shfl_xor(tsum, 32);
      l_i[ig] = l_i[ig] * alpha[ig] + tsum;
      m_i[ig] = mnew;
    }
    // O rescale, skipped when alpha==1 everywhere in the wave (numerically identical)
    if (__ballot(alpha[0] < 1.f || alpha[1] < 1.f)) {
#pragma unroll
      for (int ig = 0; ig < 2; ig++) {
        float ar[4];
#pragma unroll
        for (int rr = 0; rr < 4; rr++) ar[rr] = __shfl(alpha[ig], quad * 4 + rr);
#pragma unroll
        for (int nt = 0; nt < 8; nt++)
#pragma unroll
          for (int rr = 0; rr < 4; rr++) O[ig][nt][rr] *= ar[rr];
      }
    }
    // ---- P -> wave-private LDS (C-layout -> A-frag order) ----
#pragma unroll
    for (int ig = 0; ig < 2; ig++)
#pragma unroll
      for (int mt = 0; mt < 4; mt++) {
        unsigned lo = (unsigned)f2bf(S[ig][mt][0]) | ((unsigned)f2bf(S[ig][mt][1]) << 16);
        unsigned hi = (unsigned)f2bf(S[ig][mt][2]) | ((unsigned)f2bf(S[ig][mt][3]) << 16);
        *(uint2*)(Pw + ig * 2048 + (mt * 2 + (quad >> 1)) * 256 + l16 * 16 + (quad & 1) * 8)
            = make_uint2(lo, hi);
      }
    // intra-wave DS write->read ordering (NOT __threadfence_block: that drains vmcnt
    // and would kill the prefetch in flight)
    __asm__ __volatile__("s_waitcnt lgkmcnt(0)" ::: "memory");
    // ---- PV: O[i][c] += P[i][j] * V[j][c]; each vf feeds both i-groups ----
#pragma unroll
    for (int kt = 0; kt < 2; kt++) {
      shortx8 pf0 = *(const shortx8*)(Pw + kt * 1024 + lane * 16);
      shortx8 pf1 = *(const shortx8*)(Pw + 2048 + kt * 1024 + lane * 16);
#pragma unroll
      for (int nt = 0; nt < 8; nt++) {
        shortx8 vf = *(const shortx8*)(vc + nt * 2048 + kt * 1024 + lane * 16);
        O[0][nt] = __builtin_amdgcn_mfma_f32_16x16x32_bf16(pf0, vf, O[0][nt], 0, 0, 0);
        O[1][nt] = __builtin_amdgcn_mfma_f32_16x16x32_bf16(pf1, vf, O[1][nt], 0, 0, 0);
      }
    }
  }
  // epilogue: store partial O and (m,l)
#pragma unroll
  for (int ig = 0; ig < 2; ig++) {
    float* Ob = Opart + ((size_t)(sp * 4 + b) * HW + i0 + w * 32 + ig * 16) * 128;
#pragma unroll
    for (int nt = 0; nt < 8; nt++)
#pragma unroll
      for (int rr = 0; rr < 4; rr++)
        Ob[(size_t)(quad * 4 + rr) * 128 + nt * 16 + l16] = O[ig][nt][rr];
  }
  if (quad == 0) {
    float2* mlp = (float2*)ml;
#pragma unroll
    for (int ig = 0; ig < 2; ig++)
      mlp[(size_t)(sp * 4 + b) * HW + i0 + w * 32 + ig * 16 + l16]
          = make_float2(m_i[ig], l_i[ig]);
  }
}

// ---------------- K4: merge split-j partials -> res (flat == resmap layout) -----------
__global__ __launch_bounds__(256) void k_merge(const float* __restrict__ Opart,
    const float* __restrict__ ml, float* __restrict__ res) {
  size_t e = (size_t)blockIdx.x * 256 + threadIdx.x;  // float4 index
  int cq = (int)(e & 31);
  int i = (int)((e >> 5) & 4095);
  int b = (int)(e >> 17);
  const float2* mlp = (const float2*)ml;
  float m[SPLIT], l[SPLIT];
  float M = -1e30f;
#pragma unroll
  for (int s = 0; s < SPLIT; s++) {
    float2 st = mlp[(size_t)(s * 4 + b) * HW + i];
    m[s] = st.x; l[s] = st.y;
    M = fmaxf(M, m[s]);
  }
  float denom = 0.f;
  float wgt[SPLIT];
#pragma unroll
  for (int s = 0; s < SPLIT; s++) {
    float ws_ = EXP2F((m[s] - M) * L2E);
    wgt[s] = ws_;
    denom += l[s] * ws_;
  }
  float inv = 1.f / denom;
  floatx4 acc = {0.f, 0.f, 0.f, 0.f};
#pragma unroll
  for (int s = 0; s < SPLIT; s++) {
    floatx4 v = *(const floatx4*)(Opart + ((size_t)(s * 4 + b) * HW + i) * 128 + cq * 4);
    acc += v * (wgt[s] * inv);
  }
  *(floatx4*)(res + e * 4) = acc;
}

// ---------------- K5: conv4 (fp32) + BN(eval) + residual ------------------------------
// grid 1024 = b(4) x st(16) x cot(16); thread: 16 co x 1 px.
__global__ __launch_bounds__(256) void k_out(const float* __restrict__ res,
    const float* __restrict__ w4, const float* __restrict__ gamma,
    const float* __restrict__ beta, const float* __restrict__ rmean,
    const float* __restrict__ rvar, const float* __restrict__ x,
    float* __restrict__ out) {
  __shared__ float wt[16 * 128];
  int bid = blockIdx.x;
  int cot = bid & 15;
  int st = (bid >> 4) & 15;
  int b = bid >> 8;
  int t = threadIdx.x;
  int co0 = cot * 16;
#pragma unroll
  for (int k = 0; k < 8; k++) wt[k * 256 + t] = w4[(size_t)co0 * 128 + k * 256 + t];
  __syncthreads();
  int px = st * 256 + t;
  const float* rb = res + (size_t)b * 524288 + px;
  float acc[16];
#pragma unroll
  for (int r = 0; r < 16; r++) acc[r] = 0.f;
  for (int ci = 0; ci < 128; ci += 4) {
    float xv[4];
#pragma unroll
    for (int kk = 0; kk < 4; kk++) xv[kk] = rb[(size_t)(ci + kk) * HW];
#pragma unroll
    for (int r = 0; r < 16; r++) {
      floatx4 wv = *(const floatx4*)&wt[r * 128 + ci];
#pragma unroll
      for (int kk = 0; kk < 4; kk++) acc[r] += wv[kk] * xv[kk];
    }
  }
  const float* xb = x + ((size_t)b * 256 + co0) * HW + px;
  float* ob = out + ((size_t)b * 256 + co0) * HW + px;
#pragma unroll
  for (int r = 0; r < 16; r++) {
    int co = co0 + r;
    float g = gamma[co] * rsqrtf(rvar[co] + 1e-5f);
    float bb = beta[co] - rmean[co] * g;
    ob[(size_t)r * HW] = acc[r] * g + bb + xb[(size_t)r * HW];
  }
}

extern "C" void kernel_launch(void* const* d_in, const int* in_sizes, int n_in,
                              void* d_out, int out_size, void* d_ws, size_t ws_size,
                              hipStream_t stream) {
  const float* x     = (const float*)d_in[0];
  const float* w1    = (const float*)d_in[1];
  const float* w2    = (const float*)d_in[2];
  const float* w3    = (const float*)d_in[3];
  const float* w4    = (const float*)d_in[4];
  const float* gamma = (const float*)d_in[5];
  const float* beta  = (const float*)d_in[6];
  const float* rmean = (const float*)d_in[7];
  const float* rvar  = (const float*)d_in[8];
  float* out = (float*)d_out;
  char* ws = (char*)d_ws;

  // Opart region (32 MB) overlaps n3 / Xth / Xtl (all dead before k_flash runs)
  size_t off = (size_t)SPLIT * 4 * HW * 128 * 4;             // 32 MB
  float* Opart = (float*)ws;
  unsigned short* n3  = (unsigned short*)ws;                  // 4.2 MB @ 0
  unsigned short* Xth = (unsigned short*)(ws + ((size_t)8  << 20));  // 8.4 MB @ 8M
  unsigned short* Xtl = (unsigned short*)(ws + ((size_t)17 << 20));  // 8.4 MB @ 17M
  unsigned short* Q  = (unsigned short*)(ws + off); off += (size_t)4 * HW * 128 * 2;
  unsigned short* Kt = (unsigned short*)(ws + off); off += (size_t)4 * HW * 128 * 2;
  unsigned short* Vt = (unsigned short*)(ws + off); off += (size_t)4 * HW * 128 * 2;
  float* ml  = (float*)(ws + off); off += (size_t)SPLIT * 4 * HW * 2 * 4;
  float* res = (float*)(ws + off); off += (size_t)4 * HW * 128 * 4;
  unsigned short* Wh = (unsigned short*)(ws + off); off += (size_t)384 * 256 * 2;
  unsigned short* Wl = (unsigned short*)(ws + off); off += (size_t)384 * 256 * 2;
  if (ws_size < off) return;  // insufficient workspace: bail (validation will flag)

  k_split  <<<1036, 256, 0, stream>>>(x, w1, w2, w3, Xth, Xtl, Wh, Wl);
  k_projM  <<<768,  256, 0, stream>>>(Xth, Xtl, Wh, Wl, Q, Kt, n3);
  k_layoutV<<<256,  256, 0, stream>>>(n3, Vt);
  k_flash  <<<512,  256, 0, stream>>>(Q, Kt, Vt, Opart, ml);
  k_merge  <<<2048, 256, 0, stream>>>(Opart, ml, res);
  k_out    <<<1024, 256, 0, stream>>>(res, w4, gamma, beta, rmean, rvar, x, out);
}

// Round 9
// 191.026 us; speedup vs baseline: 1.8886x; 1.0951x over previous
//
#include <hip/hip_runtime.h>
#include <cstdint>

#define BN 4
#define CIN 256
#define HALFC 128
#define HW 4096
#define SPLIT 4
#define JT 64
#define JITERS (HW / SPLIT / JT)   // 16

typedef float  floatx4 __attribute__((ext_vector_type(4)));
typedef short  shortx8 __attribute__((ext_vector_type(8)));

#if __has_builtin(__builtin_amdgcn_exp2f)
#define EXP2F(x) __builtin_amdgcn_exp2f(x)
#else
#define EXP2F(x) exp2f(x)
#endif
#define L2E 1.44269504088896f

__device__ __forceinline__ unsigned short f2bf(float f) {
  unsigned u = __float_as_uint(f);
  u += 0x7FFFu + ((u >> 16) & 1u);   // round-to-nearest-even
  return (unsigned short)(u >> 16);
}

__device__ __forceinline__ void async16(const void* g, void* l) {
  __builtin_amdgcn_global_load_lds((const __attribute__((address_space(1))) void*)g,
                                   (__attribute__((address_space(3))) void*)l, 16, 0, 0);
}

// ---------------- K0: cast/transpose x -> Xt [b][px][ci] bf16; W -> Wh bf16 -----------
__global__ __launch_bounds__(256) void k_split(const float* __restrict__ x,
    const float* __restrict__ w1, const float* __restrict__ w2,
    const float* __restrict__ w3, unsigned short* __restrict__ Xth,
    unsigned short* __restrict__ Wh) {
  __shared__ float smf[64 * 65];
  int bid = blockIdx.x;
  int t = threadIdx.x;
  if (bid < 1024) {
    int b = bid >> 8, rem = bid & 255;
    int cit = rem >> 6, pxt = rem & 63;     // ci tile (4), px tile (64)
    const float* src = x + (size_t)b * 1048576 + (size_t)(cit * 64) * HW + pxt * 64;
#pragma unroll
    for (int k = 0; k < 16; k++) {
      int idx = k * 256 + t;
      int r = idx >> 6, c = idx & 63;
      smf[r * 65 + c] = src[(size_t)r * HW + c];
    }
    __syncthreads();
    int prow = t >> 2, seg = t & 3;
    union { unsigned short us[16]; uint4 v[2]; } oh;
#pragma unroll
    for (int u = 0; u < 16; u++)
      oh.us[u] = f2bf(smf[(seg * 16 + u) * 65 + prow]);
    size_t dst = (size_t)b * 1048576 + (size_t)(pxt * 64 + prow) * 256 + cit * 64 + seg * 16;
    *(uint4*)(Xth + dst) = oh.v[0];
    *(uint4*)(Xth + dst + 8) = oh.v[1];
  } else {
    int bw = bid - 1024;                    // 0..11, each block 8192 elems
    int f0 = bw * 8192 + t * 32;
    const float* wsrc;
    int fo;
    if (f0 < 32768)      { wsrc = w1; fo = f0; }
    else if (f0 < 65536) { wsrc = w2; fo = f0 - 32768; }
    else                 { wsrc = w3; fo = f0 - 65536; }
    union { unsigned short us[32]; uint4 v[4]; } oh;
#pragma unroll
    for (int u = 0; u < 32; u++) oh.us[u] = f2bf(wsrc[fo + u]);
#pragma unroll
    for (int k = 0; k < 4; k++) *((uint4*)(Wh + f0) + k) = oh.v[k];
  }
}

// ---------------- K1: MFMA projection (bf16, fp32 acc) ---------------------------------
__global__ __launch_bounds__(256) void k_projM(const unsigned short* __restrict__ Xth,
    const unsigned short* __restrict__ Wh, unsigned short* __restrict__ Q,
    unsigned short* __restrict__ Kt, unsigned short* __restrict__ n3) {
  __shared__ unsigned short XhS[4096];   // [128 px][32 ci] fragment order, 8 KB
  __shared__ unsigned short ES[9216];    // epilogue stage
  int bid = blockIdx.x;
  int pxt = bid & 31;
  int ct = bid >> 5;                     // b*6 + cot
  int b = ct / 6, cot = ct % 6;
  int px0 = pxt * 128, co0 = cot * 64;
  int t = threadIdx.x;
  int w = t >> 6, lane = t & 63, l16 = lane & 15, quad = lane >> 4;

  int myco = co0 + w * 16 + l16;
  shortx8 whf[8];
#pragma unroll
  for (int s = 0; s < 8; s++)
    whf[s] = *(const shortx8*)(Wh + (size_t)myco * 256 + s * 32 + quad * 8);
  floatx4 acc[8];
  floatx4 zf = {0.f, 0.f, 0.f, 0.f};
#pragma unroll
  for (int mt = 0; mt < 8; mt++) acc[mt] = zf;
  const unsigned short* XhB = Xth + (size_t)b * 1048576;
  int k8 = lane >> 4, pxm = lane & 15;

#pragma unroll
  for (int s = 0; s < 8; s++) {
    __syncthreads();
#pragma unroll
    for (int c2 = 0; c2 < 2; c2++) {     // stage fragment-order; lane L -> slot L*16
      int px = px0 + (c2 * 4 + w) * 16 + pxm;
      async16(XhB + (size_t)px * 256 + s * 32 + k8 * 8, (char*)XhS + c2 * 4096 + w * 1024);
    }
    __syncthreads();
#pragma unroll
    for (int mt = 0; mt < 8; mt++) {
      shortx8 ah = *(const shortx8*)((const char*)XhS + mt * 1024 + lane * 16);
      acc[mt] = __builtin_amdgcn_mfma_f32_16x16x32_bf16(ah, whf[s], acc[mt], 0, 0, 0);
    }
  }
  __syncthreads();
  // D layout: element [px = mt*16 + quad*4 + rr][co_l = w*16 + l16]
  if (cot < 2 || cot >= 4) {             // Q / n3: stage [co][px]
    int co_l = w * 16 + l16;
#pragma unroll
    for (int mt = 0; mt < 8; mt++) {
      int px = mt * 16 + quad * 4;
      unsigned lo = (unsigned)f2bf(acc[mt][0]) | ((unsigned)f2bf(acc[mt][1]) << 16);
      unsigned hi = (unsigned)f2bf(acc[mt][2]) | ((unsigned)f2bf(acc[mt][3]) << 16);
      *(uint2*)(ES + co_l * 136 + px) = make_uint2(lo, hi);
    }
    __syncthreads();
    int cr = t >> 2, seg = t & 3;
    unsigned short* dstb = (cot < 2)
        ? Q  + (size_t)b * 524288 + (size_t)(co0 + cr) * HW
        : n3 + (size_t)b * 524288 + (size_t)(co0 - 256 + cr) * HW;
#pragma unroll
    for (int k2 = 0; k2 < 4; k2++) {
      uint4 v = *(const uint4*)(ES + cr * 136 + seg * 32 + k2 * 8);
      *(uint4*)(dstb + px0 + seg * 32 + k2 * 8) = v;
    }
  } else {                               // Kt: stage [px][co]
#pragma unroll
    for (int mt = 0; mt < 8; mt++)
#pragma unroll
      for (int rr = 0; rr < 4; rr++) {
        int px = mt * 16 + quad * 4 + rr;
        ES[px * 72 + w * 16 + l16] = f2bf(acc[mt][rr]);
      }
    __syncthreads();
    int ch0 = co0 - 128;
#pragma unroll
    for (int it = 0; it < 4; it++) {
      int cid = it * 256 + t;
      int px = cid >> 3, c8 = cid & 7;
      uint4 v = *(const uint4*)(ES + px * 72 + c8 * 8);
      *(uint4*)(Kt + (size_t)b * 524288 + (size_t)(px0 + px) * 128 + ch0 + c8 * 8) = v;
    }
  }
}

// ---------------- K2: VtF: V in wave-fragment order for direct coalesced PV loads ------
// slot s = (nt*2+kt)*64 + quad*16 + l16 holds V[j = jt*64+kt*32+quad*8+e][c = nt*16+l16]
__global__ __launch_bounds__(256) void k_layoutVF(const unsigned short* __restrict__ n3,
    unsigned short* __restrict__ VtF) {
  __shared__ unsigned short sm[8192];
  int bid = blockIdx.x;                  // 256 = b(4) x jt(64)
  int b = bid >> 6, jt = bid & 63;
  int t = threadIdx.x;
  const unsigned short* src = n3 + (size_t)b * 524288 + (size_t)(jt * 2) * 4096;
#pragma unroll
  for (int k = 0; k < 32; k++) sm[k * 256 + t] = src[k * 256 + t];
  __syncthreads();
  unsigned short* dst = VtF + (size_t)b * 524288 + (size_t)jt * 8192;
#pragma unroll
  for (int k = 0; k < 4; k++) {
    int s = k * 256 + t;
    int nt = s >> 7, kt = (s >> 6) & 1, quad = (s >> 4) & 3, l16 = s & 15;
    union { unsigned short us[8]; uint4 v; } o;
#pragma unroll
    for (int e = 0; e < 8; e++)
      o.us[e] = sm[kt * 4096 + (quad * 8 + e) * 128 + nt * 16 + l16];
    *(uint4*)(dst + s * 8) = o.v;
  }
}

// ---------------- K3: fused flash attention ---------------------------------------------
// Wave owns 32 i. KtS double-buffered (frag order); V loaded per-fragment straight from
// global (VtF, coalesced 1KB/wave per load) — no V in LDS. Fine vmcnt pipeline:
// vf issued BEFORE Kt prefetch so vmcnt(4) drains vf while prefetch stays in flight.
__global__ __launch_bounds__(256, 2) void k_flash(const unsigned short* __restrict__ Q,
    const unsigned short* __restrict__ Kt, const unsigned short* __restrict__ VtF,
    float* __restrict__ Opart, float* __restrict__ ml) {
  __shared__ unsigned short KtS[2 * 8192];   // 2 x 16 KB
  __shared__ unsigned short PS[4 * 32 * 64]; // 16 KB (4 KB per wave)
  int bid = blockIdx.x;
  int itile = bid & 31, sp = (bid >> 5) & 3, b = bid >> 7;
  int t = threadIdx.x;
  int w = t >> 6, lane = t & 63, l16 = lane & 15, quad = lane >> 4;
  int i0 = itile * 128;

  shortx8 qf[2][4];
#pragma unroll
  for (int ig = 0; ig < 2; ig++) {
    const unsigned short* qp = Q + ((size_t)b * HW + i0 + w * 32 + ig * 16 + l16) * 128 + quad * 8;
#pragma unroll
    for (int ks = 0; ks < 4; ks++) qf[ig][ks] = *(const shortx8*)(qp + ks * 32);
  }
  __asm__ __volatile__("s_waitcnt vmcnt(0)" ::: "memory");  // drain Q loads

  floatx4 O[2][8];
  floatx4 zf = {0.f, 0.f, 0.f, 0.f};
#pragma unroll
  for (int ig = 0; ig < 2; ig++)
#pragma unroll
    for (int nt = 0; nt < 8; nt++) O[ig][nt] = zf;
  float m_i[2] = {-1e30f, -1e30f}, l_i[2] = {0.f, 0.f};

  int ccK = w * 4 + (lane >> 4);
  const unsigned short* kbase = Kt + (size_t)b * HW * 128
                              + (size_t)(sp * 1024 + l16) * 128 + ccK * 8;
  const unsigned short* vB = VtF + (size_t)b * 524288 + (size_t)(sp * 16) * 8192 + lane * 8;
  char* Pw = (char*)PS + w * 4096;

  // prologue: stage Kt tile 0 into buffer 0 (4 async16, left in flight)
#pragma unroll
  for (int c4 = 0; c4 < 4; c4++)
    async16(kbase + c4 * 2048, (char*)KtS + c4 * 4096 + w * 1024);

  for (int it = 0; it < JITERS; it++) {
    int cur = it & 1, nxt = cur ^ 1;
    // barrier A: compute(it-1) done -> KtS[nxt] free
    __asm__ __volatile__("s_barrier" ::: "memory");
    // vf loads for tile it (global, coalesced) — ISSUED BEFORE prefetch (vmcnt order!)
    shortx8 vf[8][2];
    {
      const unsigned short* vt = vB + (size_t)it * 8192;
#pragma unroll
      for (int nt = 0; nt < 8; nt++)
#pragma unroll
        for (int kt = 0; kt < 2; kt++)
          vf[nt][kt] = *(const shortx8*)(vt + (nt * 2 + kt) * 512);
    }
    if (it + 1 < JITERS) {
      const unsigned short* kp = kbase + (size_t)(it + 1) * 8192;
#pragma unroll
      for (int c4 = 0; c4 < 4; c4++)
        async16(kp + c4 * 2048, (char*)KtS + nxt * 16384 + c4 * 4096 + w * 1024);
      // drain tile-it staging only (leaves 16 vf + 4 prefetch in flight)
      __asm__ __volatile__("s_waitcnt vmcnt(20)" ::: "memory");
    } else {
      __asm__ __volatile__("s_waitcnt vmcnt(16)" ::: "memory");
    }
    // barrier B: all waves' tile-it Kt loads landed
    __asm__ __volatile__("s_barrier" ::: "memory");

    const char* kc = (const char*)KtS + cur * 16384;

    // ---- QK: S^T[j][i]; each af feeds both i-groups ----
    floatx4 S[2][4];
#pragma unroll
    for (int ig = 0; ig < 2; ig++)
#pragma unroll
      for (int mt = 0; mt < 4; mt++) S[ig][mt] = zf;
#pragma unroll
    for (int mt = 0; mt < 4; mt++) {
#pragma unroll
      for (int ks = 0; ks < 4; ks++) {
        shortx8 af = *(const shortx8*)(kc + mt * 4096 + ks * 1024 + lane * 16);
        S[0][mt] = __builtin_amdgcn_mfma_f32_16x16x32_bf16(af, qf[0][ks], S[0][mt], 0, 0, 0);
        S[1][mt] = __builtin_amdgcn_mfma_f32_16x16x32_bf16(af, qf[1][ks], S[1][mt], 0, 0, 0);
      }
    }
    // ---- online softmax per i-group; P overwrites S ----
    float alpha[2];
#pragma unroll
    for (int ig = 0; ig < 2; ig++) {
      float tmax = S[ig][0][0];
#pragma unroll
      for (int mt = 0; mt < 4; mt++)
#pragma unroll
        for (int rr = 0; rr < 4; rr++) tmax = fmaxf(tmax, S[ig][mt][rr]);
      tmax = fmaxf(tmax, __shfl_xor(tmax, 16));
      tmax = fmaxf(tmax, __shfl_xor(tmax, 32));
      float mnew = fmaxf(m_i[ig], tmax);
      alpha[ig] = EXP2F((m_i[ig] - mnew) * L2E);
      float tsum = 0.f;
#pragma unroll
      for (int mt = 0; mt < 4; mt++)
#pragma unroll
        for (int rr = 0; rr < 4; rr++) {
          float p = EXP2F((S[ig][mt][rr] - mnew) * L2E);
          S[ig][mt][rr] = p;
          tsum += p;
        }
      tsum += __shfl_xor(tsum, 16);
      tsum += __shfl_xor(tsum, 32);
      l_i[ig] = l_i[ig] * alpha[ig] + tsum;
      m_i[ig] = mnew;
    }
    if (__ballot(alpha[0] < 1.f || alpha[1] < 1.f)) {
#pragma unroll
      for (int ig = 0; ig < 2; ig++) {
        float ar[4];
#pragma unroll
        for (int rr = 0; rr < 4; rr++) ar[rr] = __shfl(alpha[ig], quad * 4 + rr);
#pragma unroll
        for (int nt = 0; nt < 8; nt++)
#pragma unroll
          for (int rr = 0; rr < 4; rr++) O[ig][nt][rr] *= ar[rr];
      }
    }
    // ---- P -> wave-private LDS; truncating bf16 pack via v_perm (1 inst/pair) ----
#pragma unroll
    for (int ig = 0; ig < 2; ig++)
#pragma unroll
      for (int mt = 0; mt < 4; mt++) {
        unsigned lo = __builtin_amdgcn_perm(__float_as_uint(S[ig][mt][1]),
                                            __float_as_uint(S[ig][mt][0]), 0x07060302u);
        unsigned hi = __builtin_amdgcn_perm(__float_as_uint(S[ig][mt][3]),
                                            __float_as_uint(S[ig][mt][2]), 0x07060302u);
        *(uint2*)(Pw + ig * 2048 + (mt * 2 + (quad >> 1)) * 256 + l16 * 16 + (quad & 1) * 8)
            = make_uint2(lo, hi);
      }
    __asm__ __volatile__("s_waitcnt lgkmcnt(0)" ::: "memory");  // PS write->read
    // vf arrival (vf older than prefetch: vmcnt(4) leaves prefetch in flight)
    if (it + 1 < JITERS) {
      __asm__ __volatile__("s_waitcnt vmcnt(4)" ::: "memory");
    } else {
      __asm__ __volatile__("s_waitcnt vmcnt(0)" ::: "memory");
    }
    // ---- PV from registers ----
#pragma unroll
    for (int kt = 0; kt < 2; kt++) {
      shortx8 pf0 = *(const shortx8*)(Pw + kt * 1024 + lane * 16);
      shortx8 pf1 = *(const shortx8*)(Pw + 2048 + kt * 1024 + lane * 16);
#pragma unroll
      for (int nt = 0; nt < 8; nt++) {
        O[0][nt] = __builtin_amdgcn_mfma_f32_16x16x32_bf16(pf0, vf[nt][kt], O[0][nt], 0, 0, 0);
        O[1][nt] = __builtin_amdgcn_mfma_f32_16x16x32_bf16(pf1, vf[nt][kt], O[1][nt], 0, 0, 0);
      }
    }
  }
  // epilogue: store partial O and (m,l)
#pragma unroll
  for (int ig = 0; ig < 2; ig++) {
    float* Ob = Opart + ((size_t)(sp * 4 + b) * HW + i0 + w * 32 + ig * 16) * 128;
#pragma unroll
    for (int nt = 0; nt < 8; nt++)
#pragma unroll
      for (int rr = 0; rr < 4; rr++)
        Ob[(size_t)(quad * 4 + rr) * 128 + nt * 16 + l16] = O[ig][nt][rr];
  }
  if (quad == 0) {
    float2* mlp = (float2*)ml;
#pragma unroll
    for (int ig = 0; ig < 2; ig++)
      mlp[(size_t)(sp * 4 + b) * HW + i0 + w * 32 + ig * 16 + l16]
          = make_float2(m_i[ig], l_i[ig]);
  }
}

// ---------------- K4: merge split-j partials -> res ------------------------------------
__global__ __launch_bounds__(256) void k_merge(const float* __restrict__ Opart,
    const float* __restrict__ ml, float* __restrict__ res) {
  size_t e = (size_t)blockIdx.x * 256 + threadIdx.x;  // float4 index
  int cq = (int)(e & 31);
  int i = (int)((e >> 5) & 4095);
  int b = (int)(e >> 17);
  const float2* mlp = (const float2*)ml;
  float m[SPLIT], l[SPLIT];
  float M = -1e30f;
#pragma unroll
  for (int s = 0; s < SPLIT; s++) {
    float2 st = mlp[(size_t)(s * 4 + b) * HW + i];
    m[s] = st.x; l[s] = st.y;
    M = fmaxf(M, m[s]);
  }
  float denom = 0.f;
  float wgt[SPLIT];
#pragma unroll
  for (int s = 0; s < SPLIT; s++) {
    float ws_ = EXP2F((m[s] - M) * L2E);
    wgt[s] = ws_;
    denom += l[s] * ws_;
  }
  float inv = 1.f / denom;
  floatx4 acc = {0.f, 0.f, 0.f, 0.f};
#pragma unroll
  for (int s = 0; s < SPLIT; s++) {
    floatx4 v = *(const floatx4*)(Opart + ((size_t)(s * 4 + b) * HW + i) * 128 + cq * 4);
    acc += v * (wgt[s] * inv);
  }
  *(floatx4*)(res + e * 4) = acc;
}

// ---------------- K5: conv4 (fp32) + BN(eval) + residual ------------------------------
__global__ __launch_bounds__(256) void k_out(const float* __restrict__ res,
    const float* __restrict__ w4, const float* __restrict__ gamma,
    const float* __restrict__ beta, const float* __restrict__ rmean,
    const float* __restrict__ rvar, const float* __restrict__ x,
    float* __restrict__ out) {
  __shared__ float wt[16 * 128];
  int bid = blockIdx.x;
  int cot = bid & 15;
  int st = (bid >> 4) & 15;
  int b = bid >> 8;
  int t = threadIdx.x;
  int co0 = cot * 16;
#pragma unroll
  for (int k = 0; k < 8; k++) wt[k * 256 + t] = w4[(size_t)co0 * 128 + k * 256 + t];
  __syncthreads();
  int px = st * 256 + t;
  const float* rb = res + (size_t)b * 524288 + px;
  float acc[16];
#pragma unroll
  for (int r = 0; r < 16; r++) acc[r] = 0.f;
  for (int ci = 0; ci < 128; ci += 4) {
    float xv[4];
#pragma unroll
    for (int kk = 0; kk < 4; kk++) xv[kk] = rb[(size_t)(ci + kk) * HW];
#pragma unroll
    for (int r = 0; r < 16; r++) {
      floatx4 wv = *(const floatx4*)&wt[r * 128 + ci];
#pragma unroll
      for (int kk = 0; kk < 4; kk++) acc[r] += wv[kk] * xv[kk];
    }
  }
  const float* xb = x + ((size_t)b * 256 + co0) * HW + px;
  float* ob = out + ((size_t)b * 256 + co0) * HW + px;
#pragma unroll
  for (int r = 0; r < 16; r++) {
    int co = co0 + r;
    float g = gamma[co] * rsqrtf(rvar[co] + 1e-5f);
    float bb = beta[co] - rmean[co] * g;
    ob[(size_t)r * HW] = acc[r] * g + bb + xb[(size_t)r * HW];
  }
}

extern "C" void kernel_launch(void* const* d_in, const int* in_sizes, int n_in,
                              void* d_out, int out_size, void* d_ws, size_t ws_size,
                              hipStream_t stream) {
  const float* x     = (const float*)d_in[0];
  const float* w1    = (const float*)d_in[1];
  const float* w2    = (const float*)d_in[2];
  const float* w3    = (const float*)d_in[3];
  const float* w4    = (const float*)d_in[4];
  const float* gamma = (const float*)d_in[5];
  const float* beta  = (const float*)d_in[6];
  const float* rmean = (const float*)d_in[7];
  const float* rvar  = (const float*)d_in[8];
  float* out = (float*)d_out;
  char* ws = (char*)d_ws;

  // Opart region (32 MB) overlaps n3 / Xth (dead before k_flash runs)
  size_t off = (size_t)SPLIT * 4 * HW * 128 * 4;             // 32 MB
  float* Opart = (float*)ws;
  unsigned short* n3  = (unsigned short*)ws;                  // 4.2 MB @ 0
  unsigned short* Xth = (unsigned short*)(ws + ((size_t)8 << 20));   // 8.4 MB @ 8M
  unsigned short* Q   = (unsigned short*)(ws + off); off += (size_t)4 * HW * 128 * 2;
  unsigned short* Kt  = (unsigned short*)(ws + off); off += (size_t)4 * HW * 128 * 2;
  unsigned short* VtF = (unsigned short*)(ws + off); off += (size_t)4 * HW * 128 * 2;
  float* ml  = (float*)(ws + off); off += (size_t)SPLIT * 4 * HW * 2 * 4;
  float* res = (float*)(ws + off); off += (size_t)4 * HW * 128 * 4;
  unsigned short* Wh = (unsigned short*)(ws + off); off += (size_t)384 * 256 * 2;
  if (ws_size < off) return;

  k_split   <<<1036, 256, 0, stream>>>(x, w1, w2, w3, Xth, Wh);
  k_projM   <<<768,  256, 0, stream>>>(Xth, Wh, Q, Kt, n3);
  k_layoutVF<<<256,  256, 0, stream>>>(n3, VtF);
  k_flash   <<<512,  256, 0, stream>>>(Q, Kt, VtF, Opart, ml);
  k_merge   <<<2048, 256, 0, stream>>>(Opart, ml, res);
  k_out     <<<1024, 256, 0, stream>>>(res, w4, gamma, beta, rmean, rvar, x, out);
}